// Round 1
// baseline (2441.787 us; speedup 1.0000x reference)
//
#include <hip/hip_runtime.h>
#include <hip/hip_bf16.h>
#include <cstdint>

#define B_  4096
#define T_  20
#define F_  32
#define E_  128
#define H_  2
#define D_  64
#define L_  3
#define HD_ 128
#define EPS_ 1e-5f

// ---------------------------------------------------------------------------
// 1. token embedding: emb[b,0,:] = mean_t(word_emb[tokens[b,t],:]) @ W_tok
// ---------------------------------------------------------------------------
__global__ __launch_bounds__(128) void tok_embed_kernel(
    const int* __restrict__ tokens, const float* __restrict__ word_emb,
    const float* __restrict__ W_tok, float* __restrict__ emb)
{
    int b = blockIdx.x;
    int tid = threadIdx.x;
    __shared__ float m[300];
    float a0 = 0.f, a1 = 0.f, a2 = 0.f;
    const int* tb = tokens + b * T_;
    for (int t = 0; t < T_; t++) {
        const float* row = word_emb + (int64_t)tb[t] * 300;
        a0 += row[tid];
        a1 += row[tid + 128];
        if (tid < 44) a2 += row[tid + 256];
    }
    m[tid]       = a0 * (1.f / T_);
    m[tid + 128] = a1 * (1.f / T_);
    if (tid < 44) m[tid + 256] = a2 * (1.f / T_);
    __syncthreads();
    float s = 0.f;
    for (int e = 0; e < 300; e++) s = fmaf(m[e], W_tok[e * E_ + tid], s);
    emb[(int64_t)b * (F_ * E_) + tid] = s;
}

// ---------------------------------------------------------------------------
// 2. field embedding gather: emb[b,1+f,:] = field_tables[f, field_ids[b,f], :]
// ---------------------------------------------------------------------------
__global__ __launch_bounds__(256) void field_gather_kernel(
    const int* __restrict__ field_ids, const float* __restrict__ field_tables,
    float* __restrict__ emb)
{
    int64_t idx = (int64_t)blockIdx.x * blockDim.x + threadIdx.x; // over B*31*32 float4
    if (idx >= (int64_t)B_ * 31 * 32) return;
    int c = (int)(idx & 31);
    int64_t tmp = idx >> 5;
    int f = (int)(tmp % 31);
    int b = (int)(tmp / 31);
    int id = field_ids[b * 31 + f];
    const float4* src = (const float4*)field_tables;
    float4 val = src[(int64_t)(f * 1000 + id) * 32 + c];
    float4* dst = (float4*)emb;
    dst[(int64_t)b * 1024 + (1 + f) * 32 + c] = val;
}

// ---------------------------------------------------------------------------
// 3. tiled fp32 GEMM with fused epilogue.
//    EPI 0: y = relu((acc - m)*rsqrt(v+eps)*g + b)     (batchnorm + relu)
//    EPI 1: y = acc + b                                 (bias only)
//    BM=BN=64, BK=32, 256 threads, 4x4 micro-tile.
// ---------------------------------------------------------------------------
template <int EPI>
__global__ __launch_bounds__(256) void gemm_epi(
    const float* __restrict__ A, const float* __restrict__ Bw, float* __restrict__ C,
    int M, int N, int K,
    const float* __restrict__ gp, const float* __restrict__ bp,
    const float* __restrict__ mp, const float* __restrict__ vp)
{
    __shared__ float As[32 * 65]; // [k][m], stride 65 to kill write conflicts
    __shared__ float Bs[32 * 64]; // [k][n]
    int tid = threadIdx.x;
    int bm = blockIdx.x, bn = blockIdx.y;
    int tx = tid & 15, ty = tid >> 4;
    float acc[4][4] = {{0.f}};
    const int64_t Abase = (int64_t)bm * 64 * K;

    for (int k0 = 0; k0 < K; k0 += 32) {
        #pragma unroll
        for (int l = 0; l < 8; l++) {
            int idx = tid + 256 * l;
            int mrow = idx >> 5, kk = idx & 31;
            As[kk * 65 + mrow] = A[Abase + (int64_t)mrow * K + k0 + kk];
        }
        #pragma unroll
        for (int l = 0; l < 8; l++) {
            int idx = tid + 256 * l;
            int kk = idx >> 6, nn = idx & 63;
            Bs[kk * 64 + nn] = Bw[(int64_t)(k0 + kk) * N + bn * 64 + nn];
        }
        __syncthreads();
        #pragma unroll
        for (int kk = 0; kk < 32; kk++) {
            float a0 = As[kk * 65 + ty * 4 + 0];
            float a1 = As[kk * 65 + ty * 4 + 1];
            float a2 = As[kk * 65 + ty * 4 + 2];
            float a3 = As[kk * 65 + ty * 4 + 3];
            float4 bv = *(const float4*)&Bs[kk * 64 + tx * 4];
            acc[0][0] = fmaf(a0, bv.x, acc[0][0]); acc[0][1] = fmaf(a0, bv.y, acc[0][1]);
            acc[0][2] = fmaf(a0, bv.z, acc[0][2]); acc[0][3] = fmaf(a0, bv.w, acc[0][3]);
            acc[1][0] = fmaf(a1, bv.x, acc[1][0]); acc[1][1] = fmaf(a1, bv.y, acc[1][1]);
            acc[1][2] = fmaf(a1, bv.z, acc[1][2]); acc[1][3] = fmaf(a1, bv.w, acc[1][3]);
            acc[2][0] = fmaf(a2, bv.x, acc[2][0]); acc[2][1] = fmaf(a2, bv.y, acc[2][1]);
            acc[2][2] = fmaf(a2, bv.z, acc[2][2]); acc[2][3] = fmaf(a2, bv.w, acc[2][3]);
            acc[3][0] = fmaf(a3, bv.x, acc[3][0]); acc[3][1] = fmaf(a3, bv.y, acc[3][1]);
            acc[3][2] = fmaf(a3, bv.z, acc[3][2]); acc[3][3] = fmaf(a3, bv.w, acc[3][3]);
        }
        __syncthreads();
    }

    // epilogue
    float sc[4], sh[4];
    #pragma unroll
    for (int c = 0; c < 4; c++) {
        int col = bn * 64 + tx * 4 + c;
        if constexpr (EPI == 0) {
            float inv = rsqrtf(vp[col] + EPS_) * gp[col];
            sc[c] = inv;
            sh[c] = bp[col] - mp[col] * inv;
        } else {
            sc[c] = 1.f;
            sh[c] = bp[col];
        }
    }
    #pragma unroll
    for (int r = 0; r < 4; r++) {
        int row = bm * 64 + ty * 4 + r;
        float4 y;
        float v0 = fmaf(acc[r][0], sc[0], sh[0]);
        float v1 = fmaf(acc[r][1], sc[1], sh[1]);
        float v2 = fmaf(acc[r][2], sc[2], sh[2]);
        float v3 = fmaf(acc[r][3], sc[3], sh[3]);
        if constexpr (EPI == 0) {
            v0 = fmaxf(v0, 0.f); v1 = fmaxf(v1, 0.f);
            v2 = fmaxf(v2, 0.f); v3 = fmaxf(v3, 0.f);
        }
        y.x = v0; y.y = v1; y.z = v2; y.w = v3;
        *(float4*)&C[(int64_t)row * N + bn * 64 + tx * 4] = y;
    }
}

// ---------------------------------------------------------------------------
// 4. fused attention layer: one block per batch row, 256 threads.
//    LDS: xs, rs(res), qs, ks, vs  (5 * 16KB = 80KB dynamic)
// ---------------------------------------------------------------------------
__device__ __forceinline__ void mm128(const float* __restrict__ W,
                                      const float* xs, float* buf, int j, int ih)
{
    float acc[16];
    #pragma unroll
    for (int r = 0; r < 16; r++) acc[r] = 0.f;
    #pragma unroll 4
    for (int e = 0; e < 128; e += 4) {
        float w0 = W[(e + 0) * HD_ + j];
        float w1 = W[(e + 1) * HD_ + j];
        float w2 = W[(e + 2) * HD_ + j];
        float w3 = W[(e + 3) * HD_ + j];
        #pragma unroll
        for (int r = 0; r < 16; r++) {
            const float4 xv = *(const float4*)&xs[(ih * 16 + r) * E_ + e];
            acc[r] = fmaf(xv.w, w3, fmaf(xv.z, w2, fmaf(xv.y, w1, fmaf(xv.x, w0, acc[r]))));
        }
    }
    #pragma unroll
    for (int r = 0; r < 16; r++) buf[(ih * 16 + r) * HD_ + j] = acc[r];
}

__global__ __launch_bounds__(256) void attn_layer_kernel(
    const float* __restrict__ xin, float* __restrict__ xout,
    const float* __restrict__ Wq, const float* __restrict__ Wk,
    const float* __restrict__ Wv, const float* __restrict__ Wres,
    const float* __restrict__ lng, const float* __restrict__ lnb)
{
    extern __shared__ float lds[];
    float* xs = lds;            // 4096
    float* rs = xs + 4096;      // res
    float* qs = rs + 4096;      // q, later softmax weights (first 2048)
    float* ks = qs + 4096;      // k, later relu(o+res)
    float* vs = ks + 4096;      // v

    int b = blockIdx.x;
    int tid = threadIdx.x;

    // stage x
    {
        const float4* xi4 = (const float4*)(xin + (int64_t)b * (F_ * E_));
        float4* xs4 = (float4*)xs;
        #pragma unroll
        for (int l = 0; l < 4; l++) xs4[tid + 256 * l] = xi4[tid + 256 * l];
    }
    __syncthreads();

    int j = tid & 127;
    int ih = tid >> 7;
    mm128(Wres, xs, rs, j, ih);
    mm128(Wq,   xs, qs, j, ih);
    mm128(Wk,   xs, ks, j, ih);
    mm128(Wv,   xs, vs, j, ih);
    __syncthreads();

    // scores: thread (srow = h*32+i, l4) handles 8 columns
    int srow = tid >> 2;
    int h = srow >> 5;
    int i = srow & 31;
    int l4 = tid & 3;
    float scr[8];
    {
        const float4* q4 = (const float4*)&qs[i * E_ + h * 64];
        #pragma unroll
        for (int jj = 0; jj < 8; jj++) {
            int jc = l4 * 8 + jj;
            const float4* k4 = (const float4*)&ks[jc * E_ + h * 64];
            float s = 0.f;
            #pragma unroll
            for (int d4 = 0; d4 < 16; d4++) {
                float4 a = q4[d4]; float4 kv = k4[d4];
                s = fmaf(a.x, kv.x, fmaf(a.y, kv.y, fmaf(a.z, kv.z, fmaf(a.w, kv.w, s))));
            }
            scr[jj] = s * 0.125f; // 1/sqrt(64)
        }
    }
    // softmax over 32 cols (4 lanes x 8 each)
    float mx = scr[0];
    #pragma unroll
    for (int jj = 1; jj < 8; jj++) mx = fmaxf(mx, scr[jj]);
    mx = fmaxf(mx, __shfl_xor(mx, 1));
    mx = fmaxf(mx, __shfl_xor(mx, 2));
    float sum = 0.f;
    #pragma unroll
    for (int jj = 0; jj < 8; jj++) { scr[jj] = __expf(scr[jj] - mx); sum += scr[jj]; }
    sum += __shfl_xor(sum, 1);
    sum += __shfl_xor(sum, 2);
    float inv = 1.f / sum;
    __syncthreads(); // everyone done reading qs/ks
    #pragma unroll
    for (int jj = 0; jj < 8; jj++) qs[h * 1024 + i * 32 + l4 * 8 + jj] = scr[jj] * inv;
    __syncthreads();

    // o = w @ v : thread owns column j, rows ih*16..+16
    int h2 = j >> 6;
    float acc[16];
    #pragma unroll
    for (int r = 0; r < 16; r++) acc[r] = 0.f;
    #pragma unroll
    for (int jk = 0; jk < 32; jk += 4) {
        float v0 = vs[(jk + 0) * HD_ + j];
        float v1 = vs[(jk + 1) * HD_ + j];
        float v2 = vs[(jk + 2) * HD_ + j];
        float v3 = vs[(jk + 3) * HD_ + j];
        #pragma unroll
        for (int r = 0; r < 16; r++) {
            float4 w4 = *(const float4*)&qs[h2 * 1024 + (ih * 16 + r) * 32 + jk];
            acc[r] = fmaf(w4.w, v3, fmaf(w4.z, v2, fmaf(w4.y, v1, fmaf(w4.x, v0, acc[r]))));
        }
    }
    // relu(o + res) into ks
    #pragma unroll
    for (int r = 0; r < 16; r++) {
        int row = ih * 16 + r;
        ks[row * HD_ + j] = fmaxf(acc[r] + rs[row * HD_ + j], 0.f);
    }
    __syncthreads();

    // layernorm over 128, 8 threads per row
    int row = tid >> 3;
    int l8 = tid & 7;
    const float4* kr = (const float4*)&ks[row * HD_ + l8 * 16];
    float4 c0 = kr[0], c1 = kr[1], c2 = kr[2], c3 = kr[3];
    float s1 = c0.x + c0.y + c0.z + c0.w + c1.x + c1.y + c1.z + c1.w
             + c2.x + c2.y + c2.z + c2.w + c3.x + c3.y + c3.z + c3.w;
    float s2 = c0.x*c0.x + c0.y*c0.y + c0.z*c0.z + c0.w*c0.w
             + c1.x*c1.x + c1.y*c1.y + c1.z*c1.z + c1.w*c1.w
             + c2.x*c2.x + c2.y*c2.y + c2.z*c2.z + c2.w*c2.w
             + c3.x*c3.x + c3.y*c3.y + c3.z*c3.z + c3.w*c3.w;
    #pragma unroll
    for (int off = 1; off < 8; off <<= 1) {
        s1 += __shfl_xor(s1, off);
        s2 += __shfl_xor(s2, off);
    }
    float mean = s1 * (1.f / 128.f);
    float var  = s2 * (1.f / 128.f) - mean * mean;
    float rstd = rsqrtf(var + EPS_);
    const float4* g4 = (const float4*)(lng + l8 * 16);
    const float4* b4 = (const float4*)(lnb + l8 * 16);
    float4* xo = (float4*)&xout[(int64_t)b * (F_ * E_) + row * HD_ + l8 * 16];
    float4 cs[4] = {c0, c1, c2, c3};
    #pragma unroll
    for (int q4i = 0; q4i < 4; q4i++) {
        float4 g = g4[q4i], bb = b4[q4i];
        float4 y;
        y.x = (cs[q4i].x - mean) * rstd * g.x + bb.x;
        y.y = (cs[q4i].y - mean) * rstd * g.y + bb.y;
        y.z = (cs[q4i].z - mean) * rstd * g.z + bb.z;
        y.w = (cs[q4i].w - mean) * rstd * g.w + bb.w;
        xo[q4i] = y;
    }
}

// ---------------------------------------------------------------------------
// 5. final: out[b] = sigmoid(concat(att,h3) . W_last + b_last)
// ---------------------------------------------------------------------------
__global__ __launch_bounds__(256) void final_kernel(
    const float* __restrict__ x, const float* __restrict__ h3,
    const float* __restrict__ Wl, const float* __restrict__ bl,
    float* __restrict__ out)
{
    int b = blockIdx.x * 4 + (threadIdx.x >> 6);
    int lane = threadIdx.x & 63;
    const float4* x4 = (const float4*)(x + (int64_t)b * 4096);
    const float4* w4 = (const float4*)Wl;
    float s = 0.f;
    for (int jj = lane; jj < 1024; jj += 64) {
        float4 a = x4[jj]; float4 w = w4[jj];
        s = fmaf(a.x, w.x, fmaf(a.y, w.y, fmaf(a.z, w.z, fmaf(a.w, w.w, s))));
    }
    const float4* h4 = (const float4*)(h3 + (int64_t)b * 128);
    if (lane < 32) {
        float4 a = h4[lane]; float4 w = w4[1024 + lane];
        s = fmaf(a.x, w.x, fmaf(a.y, w.y, fmaf(a.z, w.z, fmaf(a.w, w.w, s))));
    }
    #pragma unroll
    for (int off = 32; off; off >>= 1) s += __shfl_down(s, off);
    if (lane == 0) out[b] = 1.f / (1.f + __expf(-(s + bl[0])));
}

// ---------------------------------------------------------------------------
extern "C" void kernel_launch(void* const* d_in, const int* in_sizes, int n_in,
                              void* d_out, int out_size, void* d_ws, size_t ws_size,
                              hipStream_t stream)
{
    const int*   tokens       = (const int*)  d_in[0];
    const int*   field_ids    = (const int*)  d_in[1];
    const float* word_emb     = (const float*)d_in[2];
    const float* W_tok        = (const float*)d_in[3];
    const float* field_tables = (const float*)d_in[4];
    const float* Wq           = (const float*)d_in[5];
    const float* Wk           = (const float*)d_in[6];
    const float* Wv           = (const float*)d_in[7];
    const float* Wres         = (const float*)d_in[8];
    const float* ln_g         = (const float*)d_in[9];
    const float* ln_b         = (const float*)d_in[10];
    const float* dnn_W1       = (const float*)d_in[11];
    const float* bn1_g        = (const float*)d_in[12];
    const float* bn1_b        = (const float*)d_in[13];
    const float* bn1_m        = (const float*)d_in[14];
    const float* bn1_v        = (const float*)d_in[15];
    const float* dnn_W2       = (const float*)d_in[16];
    const float* bn2_g        = (const float*)d_in[17];
    const float* bn2_b        = (const float*)d_in[18];
    const float* bn2_m        = (const float*)d_in[19];
    const float* bn2_v        = (const float*)d_in[20];
    const float* dnn_W3       = (const float*)d_in[21];
    const float* dnn_b3       = (const float*)d_in[22];
    const float* W_last       = (const float*)d_in[23];
    const float* b_last       = (const float*)d_in[24];
    float* out = (float*)d_out;

    const int64_t embN = (int64_t)B_ * F_ * E_; // 16,777,216 floats
    float* emb  = (float*)d_ws;
    float* xbuf = emb + embN;
    float* h3   = xbuf + embN;          // 4096*128
    float* h1   = xbuf;                 // alias (dead before attention writes xbuf)
    float* h2   = xbuf + (int64_t)B_ * 1024;

    // embeddings
    tok_embed_kernel<<<B_, 128, 0, stream>>>(tokens, word_emb, W_tok, emb);
    field_gather_kernel<<<(B_ * 31 * 32) / 256, 256, 0, stream>>>(field_ids, field_tables, emb);

    // DNN tower (consumes emb before attention reuses xbuf)
    gemm_epi<0><<<dim3(B_ / 64, 1024 / 64), 256, 0, stream>>>(
        emb, dnn_W1, h1, B_, 1024, 4096, bn1_g, bn1_b, bn1_m, bn1_v);
    gemm_epi<0><<<dim3(B_ / 64, 512 / 64), 256, 0, stream>>>(
        h1, dnn_W2, h2, B_, 512, 1024, bn2_g, bn2_b, bn2_m, bn2_v);
    gemm_epi<1><<<dim3(B_ / 64, 128 / 64), 256, 0, stream>>>(
        h2, dnn_W3, h3, B_, 128, 512, nullptr, dnn_b3, nullptr, nullptr);

    // attention stack: emb -> xbuf -> emb -> xbuf
    const size_t attn_lds = 5 * 4096 * sizeof(float);
    attn_layer_kernel<<<B_, 256, attn_lds, stream>>>(
        emb, xbuf, Wq, Wk, Wv, Wres, ln_g, ln_b);
    attn_layer_kernel<<<B_, 256, attn_lds, stream>>>(
        xbuf, emb, Wq + 16384, Wk + 16384, Wv + 16384, Wres + 16384,
        ln_g + 128, ln_b + 128);
    attn_layer_kernel<<<B_, 256, attn_lds, stream>>>(
        emb, xbuf, Wq + 32768, Wk + 32768, Wv + 32768, Wres + 32768,
        ln_g + 256, ln_b + 256);

    // head
    final_kernel<<<B_ / 4, 256, 0, stream>>>(xbuf, h3, W_last, b_last, out);
}

// Round 2
// 895.145 us; speedup vs baseline: 2.7278x; 2.7278x over previous
//
#include <hip/hip_runtime.h>
#include <hip/hip_bf16.h>
#include <cstdint>

#define B_  4096
#define T_  20
#define F_  32
#define E_  128
#define H_  2
#define D_  64
#define L_  3
#define HD_ 128
#define EPS_ 1e-5f

typedef __bf16 bfv8 __attribute__((ext_vector_type(8)));
typedef __bf16 bfv4 __attribute__((ext_vector_type(4)));
typedef float  f32x4 __attribute__((ext_vector_type(4)));

__device__ __forceinline__ f32x4 mfma16(bfv8 a, bfv8 b, f32x4 c) {
    return __builtin_amdgcn_mfma_f32_16x16x32_bf16(a, b, c, 0, 0, 0);
}

// ---------------------------------------------------------------------------
// 0. pack weights into MFMA-fragment-ready bf16.
//    pk[mat][tile][ks][lane][t] = W[ks*32 + (lane>>4)*8 + t][tile*16 + (lane&15)]
//    Serves as A-frag of W^T (q/k/res transposed GEMM) and B-frag of W (v).
// ---------------------------------------------------------------------------
__global__ __launch_bounds__(256) void pack_weights_kernel(
    const float* __restrict__ Wq, const float* __restrict__ Wk,
    const float* __restrict__ Wv, const float* __restrict__ Wres,
    __bf16* __restrict__ out)
{
    int mi = blockIdx.x;   // l*4 + p
    int tile = blockIdx.y; // 0..7
    int l = mi >> 2, p = mi & 3;
    const float* Wb = (p == 0 ? Wq : p == 1 ? Wk : p == 2 ? Wv : Wres) + l * 16384;
    int tid = threadIdx.x;
    int ks = tid >> 6, lane = tid & 63;
    int l15 = lane & 15, lgg = lane >> 4;
    const float* src = Wb + (ks * 32 + lgg * 8) * HD_ + tile * 16 + l15;
    __bf16* dst = out + (int64_t)mi * 16384 + ((tile * 4 + ks) * 64 + lane) * 8;
    #pragma unroll
    for (int t = 0; t < 8; t++) dst[t] = (__bf16)src[t * HD_];
}

// ---------------------------------------------------------------------------
// 1. token embedding
// ---------------------------------------------------------------------------
__global__ __launch_bounds__(128) void tok_embed_kernel(
    const int* __restrict__ tokens, const float* __restrict__ word_emb,
    const float* __restrict__ W_tok, float* __restrict__ emb)
{
    int b = blockIdx.x;
    int tid = threadIdx.x;
    __shared__ float m[300];
    float a0 = 0.f, a1 = 0.f, a2 = 0.f;
    const int* tb = tokens + b * T_;
    for (int t = 0; t < T_; t++) {
        const float* row = word_emb + (int64_t)tb[t] * 300;
        a0 += row[tid];
        a1 += row[tid + 128];
        if (tid < 44) a2 += row[tid + 256];
    }
    m[tid]       = a0 * (1.f / T_);
    m[tid + 128] = a1 * (1.f / T_);
    if (tid < 44) m[tid + 256] = a2 * (1.f / T_);
    __syncthreads();
    float s = 0.f;
    for (int e = 0; e < 300; e++) s = fmaf(m[e], W_tok[e * E_ + tid], s);
    emb[(int64_t)b * (F_ * E_) + tid] = s;
}

// ---------------------------------------------------------------------------
// 2. field embedding gather
// ---------------------------------------------------------------------------
__global__ __launch_bounds__(256) void field_gather_kernel(
    const int* __restrict__ field_ids, const float* __restrict__ field_tables,
    float* __restrict__ emb)
{
    int64_t idx = (int64_t)blockIdx.x * blockDim.x + threadIdx.x;
    if (idx >= (int64_t)B_ * 31 * 32) return;
    int c = (int)(idx & 31);
    int64_t tmp = idx >> 5;
    int f = (int)(tmp % 31);
    int b = (int)(tmp / 31);
    int id = field_ids[b * 31 + f];
    const float4* src = (const float4*)field_tables;
    float4 val = src[(int64_t)(f * 1000 + id) * 32 + c];
    float4* dst = (float4*)emb;
    dst[(int64_t)b * 1024 + (1 + f) * 32 + c] = val;
}

// ---------------------------------------------------------------------------
// 3. fp32 GEMM with fused epilogue (DNN tower) — unchanged from round 1
// ---------------------------------------------------------------------------
template <int EPI>
__global__ __launch_bounds__(256) void gemm_epi(
    const float* __restrict__ A, const float* __restrict__ Bw, float* __restrict__ C,
    int M, int N, int K,
    const float* __restrict__ gp, const float* __restrict__ bp,
    const float* __restrict__ mp, const float* __restrict__ vp)
{
    __shared__ float As[32 * 65];
    __shared__ float Bs[32 * 64];
    int tid = threadIdx.x;
    int bm = blockIdx.x, bn = blockIdx.y;
    int tx = tid & 15, ty = tid >> 4;
    float acc[4][4] = {{0.f}};
    const int64_t Abase = (int64_t)bm * 64 * K;

    for (int k0 = 0; k0 < K; k0 += 32) {
        #pragma unroll
        for (int l = 0; l < 8; l++) {
            int idx = tid + 256 * l;
            int mrow = idx >> 5, kk = idx & 31;
            As[kk * 65 + mrow] = A[Abase + (int64_t)mrow * K + k0 + kk];
        }
        #pragma unroll
        for (int l = 0; l < 8; l++) {
            int idx = tid + 256 * l;
            int kk = idx >> 6, nn = idx & 63;
            Bs[kk * 64 + nn] = Bw[(int64_t)(k0 + kk) * N + bn * 64 + nn];
        }
        __syncthreads();
        #pragma unroll
        for (int kk = 0; kk < 32; kk++) {
            float a0 = As[kk * 65 + ty * 4 + 0];
            float a1 = As[kk * 65 + ty * 4 + 1];
            float a2 = As[kk * 65 + ty * 4 + 2];
            float a3 = As[kk * 65 + ty * 4 + 3];
            float4 bv = *(const float4*)&Bs[kk * 64 + tx * 4];
            acc[0][0] = fmaf(a0, bv.x, acc[0][0]); acc[0][1] = fmaf(a0, bv.y, acc[0][1]);
            acc[0][2] = fmaf(a0, bv.z, acc[0][2]); acc[0][3] = fmaf(a0, bv.w, acc[0][3]);
            acc[1][0] = fmaf(a1, bv.x, acc[1][0]); acc[1][1] = fmaf(a1, bv.y, acc[1][1]);
            acc[1][2] = fmaf(a1, bv.z, acc[1][2]); acc[1][3] = fmaf(a1, bv.w, acc[1][3]);
            acc[2][0] = fmaf(a2, bv.x, acc[2][0]); acc[2][1] = fmaf(a2, bv.y, acc[2][1]);
            acc[2][2] = fmaf(a2, bv.z, acc[2][2]); acc[2][3] = fmaf(a2, bv.w, acc[2][3]);
            acc[3][0] = fmaf(a3, bv.x, acc[3][0]); acc[3][1] = fmaf(a3, bv.y, acc[3][1]);
            acc[3][2] = fmaf(a3, bv.z, acc[3][2]); acc[3][3] = fmaf(a3, bv.w, acc[3][3]);
        }
        __syncthreads();
    }

    float sc[4], sh[4];
    #pragma unroll
    for (int c = 0; c < 4; c++) {
        int col = bn * 64 + tx * 4 + c;
        if constexpr (EPI == 0) {
            float inv = rsqrtf(vp[col] + EPS_) * gp[col];
            sc[c] = inv;
            sh[c] = bp[col] - mp[col] * inv;
        } else {
            sc[c] = 1.f;
            sh[c] = bp[col];
        }
    }
    #pragma unroll
    for (int r = 0; r < 4; r++) {
        int row = bm * 64 + ty * 4 + r;
        float4 y;
        float v0 = fmaf(acc[r][0], sc[0], sh[0]);
        float v1 = fmaf(acc[r][1], sc[1], sh[1]);
        float v2 = fmaf(acc[r][2], sc[2], sh[2]);
        float v3 = fmaf(acc[r][3], sc[3], sh[3]);
        if constexpr (EPI == 0) {
            v0 = fmaxf(v0, 0.f); v1 = fmaxf(v1, 0.f);
            v2 = fmaxf(v2, 0.f); v3 = fmaxf(v3, 0.f);
        }
        y.x = v0; y.y = v1; y.z = v2; y.w = v3;
        *(float4*)&C[(int64_t)row * N + bn * 64 + tx * 4] = y;
    }
}

// ---------------------------------------------------------------------------
// 4. MFMA attention layer. One block per batch row, 4 waves.
//    wave0: q^T = Wq^T x^T (scaled 1/8) -> q_lds[q][d]
//    wave1: k^T = Wk^T x^T             -> k_lds[key][d]
//    wave2: v   = x Wv                  -> vt_lds[d][key]
//    wave3: res^T = Wres^T x^T          -> r_lds[q][j] (f32)
//    then per wave (h=wid>>1, qh=wid&1):
//      S^T = k @ q^T (MFMA), softmax over keys (in-lane + shfl),
//      P^T -> p_lds (wave-private), o^T = v^T @ P^T (MFMA),
//      relu(o+res), cross-head LN via partials, store xout f32.
//    All LDS XOR-swizzled -> <=2-way bank aliasing.
// ---------------------------------------------------------------------------
__global__ __launch_bounds__(256) void attn_mfma_kernel(
    const float* __restrict__ xin, float* __restrict__ xout,
    const __bf16* __restrict__ pkw,
    const float* __restrict__ lng, const float* __restrict__ lnb)
{
    __shared__ __bf16 q_lds[32 * 128];
    __shared__ __bf16 k_lds[32 * 128];
    __shared__ __bf16 vt_lds[128 * 32];
    __shared__ float  r_lds[32 * 128];
    __shared__ __bf16 p_lds[4 * 16 * 32];
    __shared__ float  part[32 * 4];

    const int tid = threadIdx.x;
    const int wid = tid >> 6, lane = tid & 63;
    const int l15 = lane & 15, lg = lane >> 4;
    const int b = blockIdx.x;
    const float* xrow = xin + (int64_t)b * (F_ * E_);

    // ---- x fragments (same layout as A-frag and B-frag): xf[tile][ks]
    bfv8 xf[2][4];
    #pragma unroll
    for (int i = 0; i < 2; i++) {
        #pragma unroll
        for (int ks = 0; ks < 4; ks++) {
            const float* p = xrow + (i * 16 + l15) * E_ + ks * 32 + lg * 8;
            float4 u0 = *(const float4*)p;
            float4 u1 = *(const float4*)(p + 4);
            bfv8 f;
            f[0] = (__bf16)u0.x; f[1] = (__bf16)u0.y; f[2] = (__bf16)u0.z; f[3] = (__bf16)u0.w;
            f[4] = (__bf16)u1.x; f[5] = (__bf16)u1.y; f[6] = (__bf16)u1.z; f[7] = (__bf16)u1.w;
            xf[i][ks] = f;
        }
    }

    // ---- projection (64 MFMA per wave)
    const __bf16* W = pkw + wid * 16384;
    f32x4 acc[8][2];
    #pragma unroll
    for (int m = 0; m < 8; m++)
        #pragma unroll
        for (int n = 0; n < 2; n++) acc[m][n] = (f32x4){0.f, 0.f, 0.f, 0.f};

    if (wid == 2) {
        for (int m = 0; m < 8; m++) {           // m = d-tile (N dim)
            bfv8 wf[4];
            #pragma unroll
            for (int ks = 0; ks < 4; ks++)
                wf[ks] = *(const bfv8*)(W + ((m * 4 + ks) * 64 + lane) * 8);
            #pragma unroll
            for (int i = 0; i < 2; i++)
                #pragma unroll
                for (int ks = 0; ks < 4; ks++)
                    acc[m][i] = mfma16(xf[i][ks], wf[ks], acc[m][i]);
        }
    } else {
        for (int m = 0; m < 8; m++) {           // m = output-row tile (j)
            bfv8 wf[4];
            #pragma unroll
            for (int ks = 0; ks < 4; ks++)
                wf[ks] = *(const bfv8*)(W + ((m * 4 + ks) * 64 + lane) * 8);
            #pragma unroll
            for (int i = 0; i < 2; i++)
                #pragma unroll
                for (int ks = 0; ks < 4; ks++)
                    acc[m][i] = mfma16(wf[ks], xf[i][ks], acc[m][i]);
        }
    }

    // ---- store projections to LDS
    if (wid == 0) {            // q^T: C(row=j, col=q) -> q_lds[q][j], *0.125
        #pragma unroll
        for (int m = 0; m < 8; m++)
            #pragma unroll
            for (int n = 0; n < 2; n++) {
                int q = n * 16 + l15, j = m * 16 + lg * 4;
                bfv4 v4;
                #pragma unroll
                for (int r = 0; r < 4; r++) v4[r] = (__bf16)(acc[m][n][r] * 0.125f);
                *(bfv4*)&q_lds[q * 128 + (j ^ ((q & 7) << 3))] = v4;
            }
    } else if (wid == 1) {     // k^T -> k_lds[key][d]
        #pragma unroll
        for (int m = 0; m < 8; m++)
            #pragma unroll
            for (int n = 0; n < 2; n++) {
                int q = n * 16 + l15, j = m * 16 + lg * 4;
                bfv4 v4;
                #pragma unroll
                for (int r = 0; r < 4; r++) v4[r] = (__bf16)acc[m][n][r];
                *(bfv4*)&k_lds[q * 128 + (j ^ ((q & 7) << 3))] = v4;
            }
    } else if (wid == 2) {     // v: C(row=query, col=d) -> vt_lds[d][key]
        #pragma unroll
        for (int m = 0; m < 8; m++)
            #pragma unroll
            for (int i = 0; i < 2; i++) {
                int d = m * 16 + l15, key = i * 16 + lg * 4;
                bfv4 v4;
                #pragma unroll
                for (int r = 0; r < 4; r++) v4[r] = (__bf16)acc[m][i][r];
                *(bfv4*)&vt_lds[d * 32 + (key ^ (((d >> 1) & 3) << 3))] = v4;
            }
    } else {                   // res^T -> r_lds[q][j] (f32)
        #pragma unroll
        for (int m = 0; m < 8; m++)
            #pragma unroll
            for (int n = 0; n < 2; n++) {
                int q = n * 16 + l15, j = m * 16 + lg * 4;
                *(f32x4*)&r_lds[q * 128 + (j ^ ((q & 7) << 2))] = acc[m][n];
            }
    }
    __syncthreads();

    // ---- scores: S^T(32 keys x 16 queries) = k @ q^T, per (head, query-half)
    const int h = wid >> 1, qh = wid & 1;
    const int q = qh * 16 + l15;
    f32x4 sc2[2] = {(f32x4){0.f, 0.f, 0.f, 0.f}, (f32x4){0.f, 0.f, 0.f, 0.f}};
    #pragma unroll
    for (int ks = 0; ks < 2; ks++) {
        int d = h * 64 + ks * 32 + lg * 8;
        bfv8 qb = *(const bfv8*)&q_lds[q * 128 + (d ^ ((q & 7) << 3))];
        #pragma unroll
        for (int km = 0; km < 2; km++) {
            int key = km * 16 + l15;
            bfv8 kb = *(const bfv8*)&k_lds[key * 128 + (d ^ ((key & 7) << 3))];
            sc2[km] = mfma16(kb, qb, sc2[km]);
        }
    }

    // ---- softmax over 32 keys per query column
    float mx = -1e30f;
    #pragma unroll
    for (int km = 0; km < 2; km++)
        #pragma unroll
        for (int r = 0; r < 4; r++) mx = fmaxf(mx, sc2[km][r]);
    mx = fmaxf(mx, __shfl_xor(mx, 16));
    mx = fmaxf(mx, __shfl_xor(mx, 32));
    float pv[2][4];
    float sum = 0.f;
    #pragma unroll
    for (int km = 0; km < 2; km++)
        #pragma unroll
        for (int r = 0; r < 4; r++) {
            float e = __expf(sc2[km][r] - mx);
            pv[km][r] = e; sum += e;
        }
    sum += __shfl_xor(sum, 16);
    sum += __shfl_xor(sum, 32);
    float inv = 1.f / sum;

    // ---- P^T -> wave-private p_lds (no cross-wave barrier needed)
    __bf16* pw = p_lds + wid * 512;
    #pragma unroll
    for (int km = 0; km < 2; km++) {
        int key = km * 16 + lg * 4;
        bfv4 v4;
        #pragma unroll
        for (int r = 0; r < 4; r++) v4[r] = (__bf16)(pv[km][r] * inv);
        *(bfv4*)&pw[l15 * 32 + (key ^ (((l15 >> 1) & 3) << 3))] = v4;
    }

    // ---- PV: o^T(64 d x 16 q) = v^T @ P^T, K=32 in one MFMA step
    bfv8 pb = *(const bfv8*)&pw[l15 * 32 + ((lg * 8) ^ (((l15 >> 1) & 3) << 3))];
    f32x4 o[4];
    #pragma unroll
    for (int dm = 0; dm < 4; dm++) {
        int d = h * 64 + dm * 16 + l15;
        bfv8 va = *(const bfv8*)&vt_lds[d * 32 + ((lg * 8) ^ (((d >> 1) & 3) << 3))];
        o[dm] = mfma16(va, pb, (f32x4){0.f, 0.f, 0.f, 0.f});
    }

    // ---- relu(o + res), partial LN stats over this head's 64 dims
    float yv[4][4];
    float s1 = 0.f, s2 = 0.f;
    #pragma unroll
    for (int dm = 0; dm < 4; dm++) {
        int j = h * 64 + dm * 16 + lg * 4;
        f32x4 r4 = *(const f32x4*)&r_lds[q * 128 + (j ^ ((q & 7) << 2))];
        #pragma unroll
        for (int r = 0; r < 4; r++) {
            float v = fmaxf(o[dm][r] + r4[r], 0.f);
            yv[dm][r] = v;
            s1 += v; s2 += v * v;
        }
    }
    s1 += __shfl_xor(s1, 16); s1 += __shfl_xor(s1, 32);
    s2 += __shfl_xor(s2, 16); s2 += __shfl_xor(s2, 32);
    if (lg == 0) { part[q * 4 + h * 2] = s1; part[q * 4 + h * 2 + 1] = s2; }
    __syncthreads();

    // ---- layernorm across both heads (128 dims) + store
    f32x4 pt = *(const f32x4*)&part[q * 4];
    float mean = (pt[0] + pt[2]) * (1.f / 128.f);
    float var  = (pt[1] + pt[3]) * (1.f / 128.f) - mean * mean;
    float rstd = rsqrtf(var + EPS_);
    float* orow = xout + (int64_t)b * (F_ * E_) + q * HD_;
    #pragma unroll
    for (int dm = 0; dm < 4; dm++) {
        int j = h * 64 + dm * 16 + lg * 4;
        float4 g  = *(const float4*)(lng + j);
        float4 bb = *(const float4*)(lnb + j);
        float4 y;
        y.x = (yv[dm][0] - mean) * rstd * g.x + bb.x;
        y.y = (yv[dm][1] - mean) * rstd * g.y + bb.y;
        y.z = (yv[dm][2] - mean) * rstd * g.z + bb.z;
        y.w = (yv[dm][3] - mean) * rstd * g.w + bb.w;
        *(float4*)(orow + j) = y;
    }
}

// ---------------------------------------------------------------------------
// 5. final head
// ---------------------------------------------------------------------------
__global__ __launch_bounds__(256) void final_kernel(
    const float* __restrict__ x, const float* __restrict__ h3,
    const float* __restrict__ Wl, const float* __restrict__ bl,
    float* __restrict__ out)
{
    int b = blockIdx.x * 4 + (threadIdx.x >> 6);
    int lane = threadIdx.x & 63;
    const float4* x4 = (const float4*)(x + (int64_t)b * 4096);
    const float4* w4 = (const float4*)Wl;
    float s = 0.f;
    for (int jj = lane; jj < 1024; jj += 64) {
        float4 a = x4[jj]; float4 w = w4[jj];
        s = fmaf(a.x, w.x, fmaf(a.y, w.y, fmaf(a.z, w.z, fmaf(a.w, w.w, s))));
    }
    const float4* h4 = (const float4*)(h3 + (int64_t)b * 128);
    if (lane < 32) {
        float4 a = h4[lane]; float4 w = w4[1024 + lane];
        s = fmaf(a.x, w.x, fmaf(a.y, w.y, fmaf(a.z, w.z, fmaf(a.w, w.w, s))));
    }
    #pragma unroll
    for (int off = 32; off; off >>= 1) s += __shfl_down(s, off);
    if (lane == 0) out[b] = 1.f / (1.f + __expf(-(s + bl[0])));
}

// ---------------------------------------------------------------------------
extern "C" void kernel_launch(void* const* d_in, const int* in_sizes, int n_in,
                              void* d_out, int out_size, void* d_ws, size_t ws_size,
                              hipStream_t stream)
{
    const int*   tokens       = (const int*)  d_in[0];
    const int*   field_ids    = (const int*)  d_in[1];
    const float* word_emb     = (const float*)d_in[2];
    const float* W_tok        = (const float*)d_in[3];
    const float* field_tables = (const float*)d_in[4];
    const float* Wq           = (const float*)d_in[5];
    const float* Wk           = (const float*)d_in[6];
    const float* Wv           = (const float*)d_in[7];
    const float* Wres         = (const float*)d_in[8];
    const float* ln_g         = (const float*)d_in[9];
    const float* ln_b         = (const float*)d_in[10];
    const float* dnn_W1       = (const float*)d_in[11];
    const float* bn1_g        = (const float*)d_in[12];
    const float* bn1_b        = (const float*)d_in[13];
    const float* bn1_m        = (const float*)d_in[14];
    const float* bn1_v        = (const float*)d_in[15];
    const float* dnn_W2       = (const float*)d_in[16];
    const float* bn2_g        = (const float*)d_in[17];
    const float* bn2_b        = (const float*)d_in[18];
    const float* bn2_m        = (const float*)d_in[19];
    const float* bn2_v        = (const float*)d_in[20];
    const float* dnn_W3       = (const float*)d_in[21];
    const float* dnn_b3       = (const float*)d_in[22];
    const float* W_last       = (const float*)d_in[23];
    const float* b_last       = (const float*)d_in[24];
    float* out = (float*)d_out;

    const int64_t embN = (int64_t)B_ * F_ * E_;
    float* emb  = (float*)d_ws;
    float* xbuf = emb + embN;
    float* h3   = xbuf + embN;                  // 4096*128
    __bf16* pkw = (__bf16*)(h3 + (int64_t)B_ * 128);  // 12 * 16384 bf16
    float* h1   = xbuf;                          // alias, dead before attn writes xbuf
    float* h2   = xbuf + (int64_t)B_ * 1024;

    // pack weights (independent of everything else)
    pack_weights_kernel<<<dim3(12, 8), 256, 0, stream>>>(Wq, Wk, Wv, Wres, pkw);

    // embeddings
    tok_embed_kernel<<<B_, 128, 0, stream>>>(tokens, word_emb, W_tok, emb);
    field_gather_kernel<<<(B_ * 31 * 32) / 256, 256, 0, stream>>>(field_ids, field_tables, emb);

    // DNN tower (consumes emb / h1 / h2 before attention reuses xbuf)
    gemm_epi<0><<<dim3(B_ / 64, 1024 / 64), 256, 0, stream>>>(
        emb, dnn_W1, h1, B_, 1024, 4096, bn1_g, bn1_b, bn1_m, bn1_v);
    gemm_epi<0><<<dim3(B_ / 64, 512 / 64), 256, 0, stream>>>(
        h1, dnn_W2, h2, B_, 512, 1024, bn2_g, bn2_b, bn2_m, bn2_v);
    gemm_epi<1><<<dim3(B_ / 64, 128 / 64), 256, 0, stream>>>(
        h2, dnn_W3, h3, B_, 128, 512, nullptr, dnn_b3, nullptr, nullptr);

    // attention stack: emb -> xbuf -> emb -> xbuf
    attn_mfma_kernel<<<B_, 256, 0, stream>>>(emb,  xbuf, pkw,             ln_g,       ln_b);
    attn_mfma_kernel<<<B_, 256, 0, stream>>>(xbuf, emb,  pkw + 4 * 16384, ln_g + 128, ln_b + 128);
    attn_mfma_kernel<<<B_, 256, 0, stream>>>(emb,  xbuf, pkw + 8 * 16384, ln_g + 256, ln_b + 256);

    // head
    final_kernel<<<B_ / 4, 256, 0, stream>>>(xbuf, h3, W_last, b_last, out);
}

// Round 3
// 388.328 us; speedup vs baseline: 6.2880x; 2.3051x over previous
//
#include <hip/hip_runtime.h>
#include <hip/hip_bf16.h>
#include <cstdint>

#define B_  4096
#define T_  20
#define F_  32
#define E_  128
#define H_  2
#define D_  64
#define L_  3
#define HD_ 128
#define EPS_ 1e-5f

typedef __bf16 bfv8 __attribute__((ext_vector_type(8)));
typedef __bf16 bfv4 __attribute__((ext_vector_type(4)));
typedef float  f32x4 __attribute__((ext_vector_type(4)));

__device__ __forceinline__ f32x4 mfma16(bfv8 a, bfv8 b, f32x4 c) {
    return __builtin_amdgcn_mfma_f32_16x16x32_bf16(a, b, c, 0, 0, 0);
}

__device__ __forceinline__ void gload16(const __bf16* g, __bf16* l) {
    __builtin_amdgcn_global_load_lds(
        (const __attribute__((address_space(1))) void*)(g),
        (__attribute__((address_space(3))) void*)(l),
        16, 0, 0);
}

// ---------------------------------------------------------------------------
// 0a. pack attention weights into MFMA-fragment-ready bf16 (as round 2)
// ---------------------------------------------------------------------------
__global__ __launch_bounds__(256) void pack_weights_kernel(
    const float* __restrict__ Wq, const float* __restrict__ Wk,
    const float* __restrict__ Wv, const float* __restrict__ Wres,
    __bf16* __restrict__ out)
{
    int mi = blockIdx.x;   // l*4 + p
    int tile = blockIdx.y; // 0..7
    int l = mi >> 2, p = mi & 3;
    const float* Wb = (p == 0 ? Wq : p == 1 ? Wk : p == 2 ? Wv : Wres) + l * 16384;
    int tid = threadIdx.x;
    int ks = tid >> 6, lane = tid & 63;
    int l15 = lane & 15, lgg = lane >> 4;
    const float* src = Wb + (ks * 32 + lgg * 8) * HD_ + tile * 16 + l15;
    __bf16* dst = out + (int64_t)mi * 16384 + ((tile * 4 + ks) * 64 + lane) * 8;
    #pragma unroll
    for (int t = 0; t < 8; t++) dst[t] = (__bf16)src[t * HD_];
}

// ---------------------------------------------------------------------------
// 0b. transpose-pack f32 [K][N] -> bf16 [N][K] (for B^T GEMM operand)
// ---------------------------------------------------------------------------
__global__ __launch_bounds__(256) void transpose_pack_kernel(
    const float* __restrict__ in, __bf16* __restrict__ out, int K, int N)
{
    __shared__ float t[64][65];
    int k0 = blockIdx.x * 64, n0 = blockIdx.y * 64;
    int r = threadIdx.x >> 4, c = (threadIdx.x & 15) * 4;
    for (int rr = r; rr < 64; rr += 16) {
        float4 v = *(const float4*)&in[(int64_t)(k0 + rr) * N + n0 + c];
        t[rr][c] = v.x; t[rr][c + 1] = v.y; t[rr][c + 2] = v.z; t[rr][c + 3] = v.w;
    }
    __syncthreads();
    for (int rr = r; rr < 64; rr += 16) {
        bfv4 o;
        o[0] = (__bf16)t[c + 0][rr];
        o[1] = (__bf16)t[c + 1][rr];
        o[2] = (__bf16)t[c + 2][rr];
        o[3] = (__bf16)t[c + 3][rr];
        *(bfv4*)&out[(int64_t)(n0 + rr) * K + k0 + c] = o;
    }
}

// ---------------------------------------------------------------------------
// 1. token embedding -> bf16 emb row (field 0)
// ---------------------------------------------------------------------------
__global__ __launch_bounds__(128) void tok_embed_kernel(
    const int* __restrict__ tokens, const float* __restrict__ word_emb,
    const float* __restrict__ W_tok, __bf16* __restrict__ embbf)
{
    int b = blockIdx.x;
    int tid = threadIdx.x;
    __shared__ float m[300];
    float a0 = 0.f, a1 = 0.f, a2 = 0.f;
    const int* tb = tokens + b * T_;
    for (int t = 0; t < T_; t++) {
        const float* row = word_emb + (int64_t)tb[t] * 300;
        a0 += row[tid];
        a1 += row[tid + 128];
        if (tid < 44) a2 += row[tid + 256];
    }
    m[tid]       = a0 * (1.f / T_);
    m[tid + 128] = a1 * (1.f / T_);
    if (tid < 44) m[tid + 256] = a2 * (1.f / T_);
    __syncthreads();
    float s = 0.f;
    for (int e = 0; e < 300; e++) s = fmaf(m[e], W_tok[e * E_ + tid], s);
    embbf[(int64_t)b * (F_ * E_) + tid] = (__bf16)s;
}

// ---------------------------------------------------------------------------
// 2. field embedding gather -> bf16
// ---------------------------------------------------------------------------
__global__ __launch_bounds__(256) void field_gather_kernel(
    const int* __restrict__ field_ids, const float* __restrict__ field_tables,
    __bf16* __restrict__ embbf)
{
    int64_t idx = (int64_t)blockIdx.x * blockDim.x + threadIdx.x;
    if (idx >= (int64_t)B_ * 31 * 32) return;
    int c = (int)(idx & 31);
    int64_t tmp = idx >> 5;
    int f = (int)(tmp % 31);
    int b = (int)(tmp / 31);
    int id = field_ids[b * 31 + f];
    const float4* src = (const float4*)field_tables;
    float4 val = src[(int64_t)(f * 1000 + id) * 32 + c];
    bfv4 o;
    o[0] = (__bf16)val.x; o[1] = (__bf16)val.y;
    o[2] = (__bf16)val.z; o[3] = (__bf16)val.w;
    *(bfv4*)&embbf[(int64_t)b * 4096 + (1 + f) * 128 + c * 4] = o;
}

// ---------------------------------------------------------------------------
// 3a. bf16 MFMA GEMM, B^T operand, fused BN+ReLU epilogue.
//     C[M][N] = relu(bn(A[M][K] @ Bt[N][K]^T)).  BM=128, BN=64, BK=32,
//     4 waves (2x2), each 64x32 (4x2 frags, 8 MFMA/step).
//     global_load_lds w=16 staging, XOR swizzle slot^=(row>>1)&3 both sides.
//     OUTBF=1 -> bf16 out, 0 -> f32 out.
// ---------------------------------------------------------------------------
template <int OUTBF>
__global__ __launch_bounds__(256) void gemm_bt_bf16_bn(
    const __bf16* __restrict__ A, const __bf16* __restrict__ Bt,
    void* __restrict__ Cout, int M, int N, int K,
    const float* __restrict__ gp, const float* __restrict__ bp,
    const float* __restrict__ mp, const float* __restrict__ vp)
{
    __shared__ __bf16 As[128 * 32];
    __shared__ __bf16 Bs[64 * 32];
    const int tid = threadIdx.x;
    const int wid = tid >> 6, lane = tid & 63;
    const int l15 = lane & 15, lg = lane >> 4;
    const int wr = wid >> 1, wc = wid & 1;
    const int bm = blockIdx.x, bn = blockIdx.y;

    // staging: wave handles A rows wid*32..+31 (2 calls) and B rows wid*16..+15
    const int arow0 = wid * 32 + (lane >> 2);
    const int arow1 = arow0 + 16;
    const int brow  = wid * 16 + (lane >> 2);
    const int aslot0 = (lane & 3) ^ ((arow0 >> 1) & 3);
    const int aslot1 = (lane & 3) ^ ((arow1 >> 1) & 3);
    const int bslot  = (lane & 3) ^ ((brow  >> 1) & 3);
    const __bf16* Ag0 = A  + (int64_t)(bm * 128 + arow0) * K + aslot0 * 8;
    const __bf16* Ag1 = A  + (int64_t)(bm * 128 + arow1) * K + aslot1 * 8;
    const __bf16* Bg  = Bt + (int64_t)(bn * 64  + brow ) * K + bslot  * 8;
    __bf16* AsB0 = &As[(wid * 32) * 32];
    __bf16* AsB1 = &As[(wid * 32 + 16) * 32];
    __bf16* BsB  = &Bs[(wid * 16) * 32];

    // fragment read offsets (swizzled)
    int ar[4], br2[2];
    #pragma unroll
    for (int mi = 0; mi < 4; mi++) {
        int row = wr * 64 + mi * 16 + l15;
        ar[mi] = row * 32 + ((lg ^ ((row >> 1) & 3)) * 8);
    }
    #pragma unroll
    for (int ni = 0; ni < 2; ni++) {
        int row = wc * 32 + ni * 16 + l15;
        br2[ni] = row * 32 + ((lg ^ ((row >> 1) & 3)) * 8);
    }

    f32x4 acc[4][2];
    #pragma unroll
    for (int mi = 0; mi < 4; mi++)
        #pragma unroll
        for (int ni = 0; ni < 2; ni++) acc[mi][ni] = (f32x4){0.f, 0.f, 0.f, 0.f};

    for (int k0 = 0; k0 < K; k0 += 32) {
        gload16(Ag0 + k0, AsB0);
        gload16(Ag1 + k0, AsB1);
        gload16(Bg  + k0, BsB);
        __syncthreads();
        bfv8 af[4], bf2[2];
        #pragma unroll
        for (int mi = 0; mi < 4; mi++) af[mi] = *(const bfv8*)&As[ar[mi]];
        #pragma unroll
        for (int ni = 0; ni < 2; ni++) bf2[ni] = *(const bfv8*)&Bs[br2[ni]];
        #pragma unroll
        for (int mi = 0; mi < 4; mi++)
            #pragma unroll
            for (int ni = 0; ni < 2; ni++)
                acc[mi][ni] = mfma16(af[mi], bf2[ni], acc[mi][ni]);
        __syncthreads();
    }

    // fused BN + ReLU epilogue
    float inv[2], sh[2];
    #pragma unroll
    for (int ni = 0; ni < 2; ni++) {
        int col = bn * 64 + wc * 32 + ni * 16 + l15;
        float iv = rsqrtf(vp[col] + EPS_) * gp[col];
        inv[ni] = iv;
        sh[ni] = bp[col] - mp[col] * iv;
    }
    #pragma unroll
    for (int mi = 0; mi < 4; mi++)
        #pragma unroll
        for (int ni = 0; ni < 2; ni++) {
            int col = bn * 64 + wc * 32 + ni * 16 + l15;
            #pragma unroll
            for (int r = 0; r < 4; r++) {
                int row = bm * 128 + wr * 64 + mi * 16 + lg * 4 + r;
                float y = fmaxf(fmaf(acc[mi][ni][r], inv[ni], sh[ni]), 0.f);
                if constexpr (OUTBF)
                    ((__bf16*)Cout)[(int64_t)row * N + col] = (__bf16)y;
                else
                    ((float*)Cout)[(int64_t)row * N + col] = y;
            }
        }
}

// ---------------------------------------------------------------------------
// 3b. fp32 GEMM, bias epilogue (W3 only: M=4096, N=128, K=512)
// ---------------------------------------------------------------------------
__global__ __launch_bounds__(256) void gemm_bias_f32(
    const float* __restrict__ A, const float* __restrict__ Bw, float* __restrict__ C,
    int M, int N, int K, const float* __restrict__ bp)
{
    __shared__ float As[32 * 65];
    __shared__ float Bs[32 * 64];
    int tid = threadIdx.x;
    int bm = blockIdx.x, bn = blockIdx.y;
    int tx = tid & 15, ty = tid >> 4;
    float acc[4][4] = {{0.f}};
    const int64_t Abase = (int64_t)bm * 64 * K;

    for (int k0 = 0; k0 < K; k0 += 32) {
        #pragma unroll
        for (int l = 0; l < 8; l++) {
            int idx = tid + 256 * l;
            int mrow = idx >> 5, kk = idx & 31;
            As[kk * 65 + mrow] = A[Abase + (int64_t)mrow * K + k0 + kk];
        }
        #pragma unroll
        for (int l = 0; l < 8; l++) {
            int idx = tid + 256 * l;
            int kk = idx >> 6, nn = idx & 63;
            Bs[kk * 64 + nn] = Bw[(int64_t)(k0 + kk) * N + bn * 64 + nn];
        }
        __syncthreads();
        #pragma unroll
        for (int kk = 0; kk < 32; kk++) {
            float a0 = As[kk * 65 + ty * 4 + 0];
            float a1 = As[kk * 65 + ty * 4 + 1];
            float a2 = As[kk * 65 + ty * 4 + 2];
            float a3 = As[kk * 65 + ty * 4 + 3];
            float4 bv = *(const float4*)&Bs[kk * 64 + tx * 4];
            acc[0][0] = fmaf(a0, bv.x, acc[0][0]); acc[0][1] = fmaf(a0, bv.y, acc[0][1]);
            acc[0][2] = fmaf(a0, bv.z, acc[0][2]); acc[0][3] = fmaf(a0, bv.w, acc[0][3]);
            acc[1][0] = fmaf(a1, bv.x, acc[1][0]); acc[1][1] = fmaf(a1, bv.y, acc[1][1]);
            acc[1][2] = fmaf(a1, bv.z, acc[1][2]); acc[1][3] = fmaf(a1, bv.w, acc[1][3]);
            acc[2][0] = fmaf(a2, bv.x, acc[2][0]); acc[2][1] = fmaf(a2, bv.y, acc[2][1]);
            acc[2][2] = fmaf(a2, bv.z, acc[2][2]); acc[2][3] = fmaf(a2, bv.w, acc[2][3]);
            acc[3][0] = fmaf(a3, bv.x, acc[3][0]); acc[3][1] = fmaf(a3, bv.y, acc[3][1]);
            acc[3][2] = fmaf(a3, bv.z, acc[3][2]); acc[3][3] = fmaf(a3, bv.w, acc[3][3]);
        }
        __syncthreads();
    }
    #pragma unroll
    for (int r = 0; r < 4; r++) {
        int row = bm * 64 + ty * 4 + r;
        float4 y;
        y.x = acc[r][0] + bp[bn * 64 + tx * 4 + 0];
        y.y = acc[r][1] + bp[bn * 64 + tx * 4 + 1];
        y.z = acc[r][2] + bp[bn * 64 + tx * 4 + 2];
        y.w = acc[r][3] + bp[bn * 64 + tx * 4 + 3];
        *(float4*)&C[(int64_t)row * N + bn * 64 + tx * 4] = y;
    }
}

// ---------------------------------------------------------------------------
// 4. MFMA attention layer (round-2 verified body), templated input dtype.
//    XBF=1: xin is bf16; XBF=0: xin is f32.  In-place safe (row-local).
// ---------------------------------------------------------------------------
template <int XBF>
__global__ __launch_bounds__(256) void attn_mfma_kernel(
    const void* __restrict__ xin_, float* __restrict__ xout,
    const __bf16* __restrict__ pkw,
    const float* __restrict__ lng, const float* __restrict__ lnb)
{
    __shared__ __bf16 q_lds[32 * 128];
    __shared__ __bf16 k_lds[32 * 128];
    __shared__ __bf16 vt_lds[128 * 32];
    __shared__ float  r_lds[32 * 128];
    __shared__ __bf16 p_lds[4 * 16 * 32];
    __shared__ float  part[32 * 4];

    const int tid = threadIdx.x;
    const int wid = tid >> 6, lane = tid & 63;
    const int l15 = lane & 15, lg = lane >> 4;
    const int b = blockIdx.x;

    // ---- x fragments
    bfv8 xf[2][4];
    if constexpr (XBF) {
        const __bf16* xrow = (const __bf16*)xin_ + (int64_t)b * (F_ * E_);
        #pragma unroll
        for (int i = 0; i < 2; i++)
            #pragma unroll
            for (int ks = 0; ks < 4; ks++)
                xf[i][ks] = *(const bfv8*)&xrow[(i * 16 + l15) * E_ + ks * 32 + lg * 8];
    } else {
        const float* xrow = (const float*)xin_ + (int64_t)b * (F_ * E_);
        #pragma unroll
        for (int i = 0; i < 2; i++)
            #pragma unroll
            for (int ks = 0; ks < 4; ks++) {
                const float* p = xrow + (i * 16 + l15) * E_ + ks * 32 + lg * 8;
                float4 u0 = *(const float4*)p;
                float4 u1 = *(const float4*)(p + 4);
                bfv8 f;
                f[0] = (__bf16)u0.x; f[1] = (__bf16)u0.y; f[2] = (__bf16)u0.z; f[3] = (__bf16)u0.w;
                f[4] = (__bf16)u1.x; f[5] = (__bf16)u1.y; f[6] = (__bf16)u1.z; f[7] = (__bf16)u1.w;
                xf[i][ks] = f;
            }
    }

    // ---- projection (64 MFMA per wave)
    const __bf16* W = pkw + wid * 16384;
    f32x4 acc[8][2];
    #pragma unroll
    for (int m = 0; m < 8; m++)
        #pragma unroll
        for (int n = 0; n < 2; n++) acc[m][n] = (f32x4){0.f, 0.f, 0.f, 0.f};

    if (wid == 2) {
        for (int m = 0; m < 8; m++) {
            bfv8 wf[4];
            #pragma unroll
            for (int ks = 0; ks < 4; ks++)
                wf[ks] = *(const bfv8*)(W + ((m * 4 + ks) * 64 + lane) * 8);
            #pragma unroll
            for (int i = 0; i < 2; i++)
                #pragma unroll
                for (int ks = 0; ks < 4; ks++)
                    acc[m][i] = mfma16(xf[i][ks], wf[ks], acc[m][i]);
        }
    } else {
        for (int m = 0; m < 8; m++) {
            bfv8 wf[4];
            #pragma unroll
            for (int ks = 0; ks < 4; ks++)
                wf[ks] = *(const bfv8*)(W + ((m * 4 + ks) * 64 + lane) * 8);
            #pragma unroll
            for (int i = 0; i < 2; i++)
                #pragma unroll
                for (int ks = 0; ks < 4; ks++)
                    acc[m][i] = mfma16(wf[ks], xf[i][ks], acc[m][i]);
        }
    }

    // ---- store projections to LDS
    if (wid == 0) {
        #pragma unroll
        for (int m = 0; m < 8; m++)
            #pragma unroll
            for (int n = 0; n < 2; n++) {
                int q = n * 16 + l15, j = m * 16 + lg * 4;
                bfv4 v4;
                #pragma unroll
                for (int r = 0; r < 4; r++) v4[r] = (__bf16)(acc[m][n][r] * 0.125f);
                *(bfv4*)&q_lds[q * 128 + (j ^ ((q & 7) << 3))] = v4;
            }
    } else if (wid == 1) {
        #pragma unroll
        for (int m = 0; m < 8; m++)
            #pragma unroll
            for (int n = 0; n < 2; n++) {
                int q = n * 16 + l15, j = m * 16 + lg * 4;
                bfv4 v4;
                #pragma unroll
                for (int r = 0; r < 4; r++) v4[r] = (__bf16)acc[m][n][r];
                *(bfv4*)&k_lds[q * 128 + (j ^ ((q & 7) << 3))] = v4;
            }
    } else if (wid == 2) {
        #pragma unroll
        for (int m = 0; m < 8; m++)
            #pragma unroll
            for (int i = 0; i < 2; i++) {
                int d = m * 16 + l15, key = i * 16 + lg * 4;
                bfv4 v4;
                #pragma unroll
                for (int r = 0; r < 4; r++) v4[r] = (__bf16)acc[m][i][r];
                *(bfv4*)&vt_lds[d * 32 + (key ^ (((d >> 1) & 3) << 3))] = v4;
            }
    } else {
        #pragma unroll
        for (int m = 0; m < 8; m++)
            #pragma unroll
            for (int n = 0; n < 2; n++) {
                int q = n * 16 + l15, j = m * 16 + lg * 4;
                *(f32x4*)&r_lds[q * 128 + (j ^ ((q & 7) << 2))] = acc[m][n];
            }
    }
    __syncthreads();

    // ---- scores S^T = k @ q^T per (head, query-half)
    const int h = wid >> 1, qh = wid & 1;
    const int q = qh * 16 + l15;
    f32x4 sc2[2] = {(f32x4){0.f, 0.f, 0.f, 0.f}, (f32x4){0.f, 0.f, 0.f, 0.f}};
    #pragma unroll
    for (int ks = 0; ks < 2; ks++) {
        int d = h * 64 + ks * 32 + lg * 8;
        bfv8 qb = *(const bfv8*)&q_lds[q * 128 + (d ^ ((q & 7) << 3))];
        #pragma unroll
        for (int km = 0; km < 2; km++) {
            int key = km * 16 + l15;
            bfv8 kb = *(const bfv8*)&k_lds[key * 128 + (d ^ ((key & 7) << 3))];
            sc2[km] = mfma16(kb, qb, sc2[km]);
        }
    }

    // ---- softmax over 32 keys
    float mx = -1e30f;
    #pragma unroll
    for (int km = 0; km < 2; km++)
        #pragma unroll
        for (int r = 0; r < 4; r++) mx = fmaxf(mx, sc2[km][r]);
    mx = fmaxf(mx, __shfl_xor(mx, 16));
    mx = fmaxf(mx, __shfl_xor(mx, 32));
    float pv[2][4];
    float sum = 0.f;
    #pragma unroll
    for (int km = 0; km < 2; km++)
        #pragma unroll
        for (int r = 0; r < 4; r++) {
            float e = __expf(sc2[km][r] - mx);
            pv[km][r] = e; sum += e;
        }
    sum += __shfl_xor(sum, 16);
    sum += __shfl_xor(sum, 32);
    float inv = 1.f / sum;

    // ---- P^T -> wave-private p_lds
    __bf16* pw = p_lds + wid * 512;
    #pragma unroll
    for (int km = 0; km < 2; km++) {
        int key = km * 16 + lg * 4;
        bfv4 v4;
        #pragma unroll
        for (int r = 0; r < 4; r++) v4[r] = (__bf16)(pv[km][r] * inv);
        *(bfv4*)&pw[l15 * 32 + (key ^ (((l15 >> 1) & 3) << 3))] = v4;
    }

    // ---- PV: o^T = v^T @ P^T
    bfv8 pb = *(const bfv8*)&pw[l15 * 32 + ((lg * 8) ^ (((l15 >> 1) & 3) << 3))];
    f32x4 o[4];
    #pragma unroll
    for (int dm = 0; dm < 4; dm++) {
        int d = h * 64 + dm * 16 + l15;
        bfv8 va = *(const bfv8*)&vt_lds[d * 32 + ((lg * 8) ^ (((d >> 1) & 3) << 3))];
        o[dm] = mfma16(va, pb, (f32x4){0.f, 0.f, 0.f, 0.f});
    }

    // ---- relu(o + res), partial LN stats
    float yv[4][4];
    float s1 = 0.f, s2 = 0.f;
    #pragma unroll
    for (int dm = 0; dm < 4; dm++) {
        int j = h * 64 + dm * 16 + lg * 4;
        f32x4 r4 = *(const f32x4*)&r_lds[q * 128 + (j ^ ((q & 7) << 2))];
        #pragma unroll
        for (int r = 0; r < 4; r++) {
            float v = fmaxf(o[dm][r] + r4[r], 0.f);
            yv[dm][r] = v;
            s1 += v; s2 += v * v;
        }
    }
    s1 += __shfl_xor(s1, 16); s1 += __shfl_xor(s1, 32);
    s2 += __shfl_xor(s2, 16); s2 += __shfl_xor(s2, 32);
    if (lg == 0) { part[q * 4 + h * 2] = s1; part[q * 4 + h * 2 + 1] = s2; }
    __syncthreads();

    // ---- layernorm + store f32
    f32x4 pt = *(const f32x4*)&part[q * 4];
    float mean = (pt[0] + pt[2]) * (1.f / 128.f);
    float var  = (pt[1] + pt[3]) * (1.f / 128.f) - mean * mean;
    float rstd = rsqrtf(var + EPS_);
    float* orow = xout + (int64_t)b * (F_ * E_) + q * HD_;
    #pragma unroll
    for (int dm = 0; dm < 4; dm++) {
        int j = h * 64 + dm * 16 + lg * 4;
        float4 g  = *(const float4*)(lng + j);
        float4 bb = *(const float4*)(lnb + j);
        float4 y;
        y.x = (yv[dm][0] - mean) * rstd * g.x + bb.x;
        y.y = (yv[dm][1] - mean) * rstd * g.y + bb.y;
        y.z = (yv[dm][2] - mean) * rstd * g.z + bb.z;
        y.w = (yv[dm][3] - mean) * rstd * g.w + bb.w;
        *(float4*)(orow + j) = y;
    }
}

// ---------------------------------------------------------------------------
// 5. final head
// ---------------------------------------------------------------------------
__global__ __launch_bounds__(256) void final_kernel(
    const float* __restrict__ x, const float* __restrict__ h3,
    const float* __restrict__ Wl, const float* __restrict__ bl,
    float* __restrict__ out)
{
    int b = blockIdx.x * 4 + (threadIdx.x >> 6);
    int lane = threadIdx.x & 63;
    const float4* x4 = (const float4*)(x + (int64_t)b * 4096);
    const float4* w4 = (const float4*)Wl;
    float s = 0.f;
    for (int jj = lane; jj < 1024; jj += 64) {
        float4 a = x4[jj]; float4 w = w4[jj];
        s = fmaf(a.x, w.x, fmaf(a.y, w.y, fmaf(a.z, w.z, fmaf(a.w, w.w, s))));
    }
    const float4* h4 = (const float4*)(h3 + (int64_t)b * 128);
    if (lane < 32) {
        float4 a = h4[lane]; float4 w = w4[1024 + lane];
        s = fmaf(a.x, w.x, fmaf(a.y, w.y, fmaf(a.z, w.z, fmaf(a.w, w.w, s))));
    }
    #pragma unroll
    for (int off = 32; off; off >>= 1) s += __shfl_down(s, off);
    if (lane == 0) out[b] = 1.f / (1.f + __expf(-(s + bl[0])));
}

// ---------------------------------------------------------------------------
extern "C" void kernel_launch(void* const* d_in, const int* in_sizes, int n_in,
                              void* d_out, int out_size, void* d_ws, size_t ws_size,
                              hipStream_t stream)
{
    const int*   tokens       = (const int*)  d_in[0];
    const int*   field_ids    = (const int*)  d_in[1];
    const float* word_emb     = (const float*)d_in[2];
    const float* W_tok        = (const float*)d_in[3];
    const float* field_tables = (const float*)d_in[4];
    const float* Wq           = (const float*)d_in[5];
    const float* Wk           = (const float*)d_in[6];
    const float* Wv           = (const float*)d_in[7];
    const float* Wres         = (const float*)d_in[8];
    const float* ln_g         = (const float*)d_in[9];
    const float* ln_b         = (const float*)d_in[10];
    const float* dnn_W1       = (const float*)d_in[11];
    const float* bn1_g        = (const float*)d_in[12];
    const float* bn1_b        = (const float*)d_in[13];
    const float* bn1_m        = (const float*)d_in[14];
    const float* bn1_v        = (const float*)d_in[15];
    const float* dnn_W2       = (const float*)d_in[16];
    const float* bn2_g        = (const float*)d_in[17];
    const float* bn2_b        = (const float*)d_in[18];
    const float* bn2_m        = (const float*)d_in[19];
    const float* bn2_v        = (const float*)d_in[20];
    const float* dnn_W3       = (const float*)d_in[21];
    const float* dnn_b3       = (const float*)d_in[22];
    const float* W_last       = (const float*)d_in[23];
    const float* b_last       = (const float*)d_in[24];
    float* out = (float*)d_out;

    const int64_t embN = (int64_t)B_ * F_ * E_;        // 16,777,216
    float*  xbuf  = (float*)d_ws;                       // 64 MB (attn f32 x)
    __bf16* embbf = (__bf16*)(xbuf + embN);             // 32 MB
    float*  h3    = (float*)(embbf + embN);             // 2 MB
    __bf16* pkw   = (__bf16*)(h3 + (int64_t)B_ * 128);  // 12*16384 bf16
    __bf16* W1t   = pkw + 12 * 16384;                   // [1024][4096] bf16, 8 MB
    __bf16* W2t   = W1t + (int64_t)1024 * 4096;         // [512][1024] bf16, 1 MB
    // DNN intermediates alias xbuf (dead before attention writes xbuf)
    __bf16* h1bf  = (__bf16*)xbuf;                      // [4096][1024] bf16, 8 MB
    float*  h2f   = xbuf + (int64_t)4 * 1024 * 1024;    // [4096][512] f32, 8 MB

    // weight packing
    pack_weights_kernel<<<dim3(12, 8), 256, 0, stream>>>(Wq, Wk, Wv, Wres, pkw);
    transpose_pack_kernel<<<dim3(64, 16), 256, 0, stream>>>(dnn_W1, W1t, 4096, 1024);
    transpose_pack_kernel<<<dim3(16, 8), 256, 0, stream>>>(dnn_W2, W2t, 1024, 512);

    // embeddings (bf16)
    tok_embed_kernel<<<B_, 128, 0, stream>>>(tokens, word_emb, W_tok, embbf);
    field_gather_kernel<<<(B_ * 31 * 32) / 256, 256, 0, stream>>>(field_ids, field_tables, embbf);

    // DNN tower: bf16 MFMA W1, W2; fp32 W3
    gemm_bt_bf16_bn<1><<<dim3(32, 16), 256, 0, stream>>>(
        embbf, W1t, h1bf, B_, 1024, 4096, bn1_g, bn1_b, bn1_m, bn1_v);
    gemm_bt_bf16_bn<0><<<dim3(32, 8), 256, 0, stream>>>(
        h1bf, W2t, h2f, B_, 512, 1024, bn2_g, bn2_b, bn2_m, bn2_v);
    gemm_bias_f32<<<dim3(64, 2), 256, 0, stream>>>(
        h2f, dnn_W3, h3, B_, 128, 512, dnn_b3);

    // attention stack: embbf -> xbuf, then in-place (row-local kernel)
    attn_mfma_kernel<1><<<B_, 256, 0, stream>>>(embbf, xbuf, pkw,             ln_g,       ln_b);
    attn_mfma_kernel<0><<<B_, 256, 0, stream>>>(xbuf,  xbuf, pkw + 4 * 16384, ln_g + 128, ln_b + 128);
    attn_mfma_kernel<0><<<B_, 256, 0, stream>>>(xbuf,  xbuf, pkw + 8 * 16384, ln_g + 256, ln_b + 256);

    // head
    final_kernel<<<B_ / 4, 256, 0, stream>>>(xbuf, h3, W_last, b_last, out);
}

// Round 4
// 302.782 us; speedup vs baseline: 8.0645x; 1.2825x over previous
//
#include <hip/hip_runtime.h>
#include <hip/hip_bf16.h>
#include <cstdint>

#define B_  4096
#define T_  20
#define F_  32
#define E_  128
#define H_  2
#define D_  64
#define L_  3
#define HD_ 128
#define EPS_ 1e-5f

typedef __bf16 bfv8 __attribute__((ext_vector_type(8)));
typedef __bf16 bfv4 __attribute__((ext_vector_type(4)));
typedef float  f32x4 __attribute__((ext_vector_type(4)));

__device__ __forceinline__ f32x4 mfma16(bfv8 a, bfv8 b, f32x4 c) {
    return __builtin_amdgcn_mfma_f32_16x16x32_bf16(a, b, c, 0, 0, 0);
}

__device__ __forceinline__ void gload16(const __bf16* g, __bf16* l) {
    __builtin_amdgcn_global_load_lds(
        (const __attribute__((address_space(1))) void*)(g),
        (__attribute__((address_space(3))) void*)(l),
        16, 0, 0);
}

// ---------------------------------------------------------------------------
// 0a. pack attention weights into MFMA-fragment-ready bf16
// ---------------------------------------------------------------------------
__global__ __launch_bounds__(256) void pack_weights_kernel(
    const float* __restrict__ Wq, const float* __restrict__ Wk,
    const float* __restrict__ Wv, const float* __restrict__ Wres,
    __bf16* __restrict__ out)
{
    int mi = blockIdx.x;   // l*4 + p
    int tile = blockIdx.y; // 0..7
    int l = mi >> 2, p = mi & 3;
    const float* Wb = (p == 0 ? Wq : p == 1 ? Wk : p == 2 ? Wv : Wres) + l * 16384;
    int tid = threadIdx.x;
    int ks = tid >> 6, lane = tid & 63;
    int l15 = lane & 15, lgg = lane >> 4;
    const float* src = Wb + (ks * 32 + lgg * 8) * HD_ + tile * 16 + l15;
    __bf16* dst = out + (int64_t)mi * 16384 + ((tile * 4 + ks) * 64 + lane) * 8;
    #pragma unroll
    for (int t = 0; t < 8; t++) dst[t] = (__bf16)src[t * HD_];
}

// ---------------------------------------------------------------------------
// 0b. transpose-pack f32 [K][N] -> bf16 [N][K]
// ---------------------------------------------------------------------------
__global__ __launch_bounds__(256) void transpose_pack_kernel(
    const float* __restrict__ in, __bf16* __restrict__ out, int K, int N)
{
    __shared__ float t[64][65];
    int k0 = blockIdx.x * 64, n0 = blockIdx.y * 64;
    int r = threadIdx.x >> 4, c = (threadIdx.x & 15) * 4;
    for (int rr = r; rr < 64; rr += 16) {
        float4 v = *(const float4*)&in[(int64_t)(k0 + rr) * N + n0 + c];
        t[rr][c] = v.x; t[rr][c + 1] = v.y; t[rr][c + 2] = v.z; t[rr][c + 3] = v.w;
    }
    __syncthreads();
    for (int rr = r; rr < 64; rr += 16) {
        bfv4 o;
        o[0] = (__bf16)t[c + 0][rr];
        o[1] = (__bf16)t[c + 1][rr];
        o[2] = (__bf16)t[c + 2][rr];
        o[3] = (__bf16)t[c + 3][rr];
        *(bfv4*)&out[(int64_t)(n0 + rr) * K + k0 + c] = o;
    }
}

// ---------------------------------------------------------------------------
// 1. token embedding -> bf16 emb row (field 0)
// ---------------------------------------------------------------------------
__global__ __launch_bounds__(128) void tok_embed_kernel(
    const int* __restrict__ tokens, const float* __restrict__ word_emb,
    const float* __restrict__ W_tok, __bf16* __restrict__ embbf)
{
    int b = blockIdx.x;
    int tid = threadIdx.x;
    __shared__ float m[300];
    float a0 = 0.f, a1 = 0.f, a2 = 0.f;
    const int* tb = tokens + b * T_;
    for (int t = 0; t < T_; t++) {
        const float* row = word_emb + (int64_t)tb[t] * 300;
        a0 += row[tid];
        a1 += row[tid + 128];
        if (tid < 44) a2 += row[tid + 256];
    }
    m[tid]       = a0 * (1.f / T_);
    m[tid + 128] = a1 * (1.f / T_);
    if (tid < 44) m[tid + 256] = a2 * (1.f / T_);
    __syncthreads();
    float s = 0.f;
    for (int e = 0; e < 300; e++) s = fmaf(m[e], W_tok[e * E_ + tid], s);
    embbf[(int64_t)b * (F_ * E_) + tid] = (__bf16)s;
}

// ---------------------------------------------------------------------------
// 2. field embedding gather -> bf16
// ---------------------------------------------------------------------------
__global__ __launch_bounds__(256) void field_gather_kernel(
    const int* __restrict__ field_ids, const float* __restrict__ field_tables,
    __bf16* __restrict__ embbf)
{
    int64_t idx = (int64_t)blockIdx.x * blockDim.x + threadIdx.x;
    if (idx >= (int64_t)B_ * 31 * 32) return;
    int c = (int)(idx & 31);
    int64_t tmp = idx >> 5;
    int f = (int)(tmp % 31);
    int b = (int)(tmp / 31);
    int id = field_ids[b * 31 + f];
    const float4* src = (const float4*)field_tables;
    float4 val = src[(int64_t)(f * 1000 + id) * 32 + c];
    bfv4 o;
    o[0] = (__bf16)val.x; o[1] = (__bf16)val.y;
    o[2] = (__bf16)val.z; o[3] = (__bf16)val.w;
    *(bfv4*)&embbf[(int64_t)b * 4096 + (1 + f) * 128 + c * 4] = o;
}

// ---------------------------------------------------------------------------
// 3a. bf16 MFMA GEMM, B^T operand, fused BN+ReLU epilogue (W1, W2)
// ---------------------------------------------------------------------------
template <int OUTBF>
__global__ __launch_bounds__(256) void gemm_bt_bf16_bn(
    const __bf16* __restrict__ A, const __bf16* __restrict__ Bt,
    void* __restrict__ Cout, int M, int N, int K,
    const float* __restrict__ gp, const float* __restrict__ bp,
    const float* __restrict__ mp, const float* __restrict__ vp)
{
    __shared__ __bf16 As[128 * 32];
    __shared__ __bf16 Bs[64 * 32];
    const int tid = threadIdx.x;
    const int wid = tid >> 6, lane = tid & 63;
    const int l15 = lane & 15, lg = lane >> 4;
    const int wr = wid >> 1, wc = wid & 1;
    const int bm = blockIdx.x, bn = blockIdx.y;

    const int arow0 = wid * 32 + (lane >> 2);
    const int arow1 = arow0 + 16;
    const int brow  = wid * 16 + (lane >> 2);
    const int aslot0 = (lane & 3) ^ ((arow0 >> 1) & 3);
    const int aslot1 = (lane & 3) ^ ((arow1 >> 1) & 3);
    const int bslot  = (lane & 3) ^ ((brow  >> 1) & 3);
    const __bf16* Ag0 = A  + (int64_t)(bm * 128 + arow0) * K + aslot0 * 8;
    const __bf16* Ag1 = A  + (int64_t)(bm * 128 + arow1) * K + aslot1 * 8;
    const __bf16* Bg  = Bt + (int64_t)(bn * 64  + brow ) * K + bslot  * 8;
    __bf16* AsB0 = &As[(wid * 32) * 32];
    __bf16* AsB1 = &As[(wid * 32 + 16) * 32];
    __bf16* BsB  = &Bs[(wid * 16) * 32];

    int ar[4], br2[2];
    #pragma unroll
    for (int mi = 0; mi < 4; mi++) {
        int row = wr * 64 + mi * 16 + l15;
        ar[mi] = row * 32 + ((lg ^ ((row >> 1) & 3)) * 8);
    }
    #pragma unroll
    for (int ni = 0; ni < 2; ni++) {
        int row = wc * 32 + ni * 16 + l15;
        br2[ni] = row * 32 + ((lg ^ ((row >> 1) & 3)) * 8);
    }

    f32x4 acc[4][2];
    #pragma unroll
    for (int mi = 0; mi < 4; mi++)
        #pragma unroll
        for (int ni = 0; ni < 2; ni++) acc[mi][ni] = (f32x4){0.f, 0.f, 0.f, 0.f};

    for (int k0 = 0; k0 < K; k0 += 32) {
        gload16(Ag0 + k0, AsB0);
        gload16(Ag1 + k0, AsB1);
        gload16(Bg  + k0, BsB);
        __syncthreads();
        bfv8 af[4], bf2[2];
        #pragma unroll
        for (int mi = 0; mi < 4; mi++) af[mi] = *(const bfv8*)&As[ar[mi]];
        #pragma unroll
        for (int ni = 0; ni < 2; ni++) bf2[ni] = *(const bfv8*)&Bs[br2[ni]];
        #pragma unroll
        for (int mi = 0; mi < 4; mi++)
            #pragma unroll
            for (int ni = 0; ni < 2; ni++)
                acc[mi][ni] = mfma16(af[mi], bf2[ni], acc[mi][ni]);
        __syncthreads();
    }

    float inv[2], sh[2];
    #pragma unroll
    for (int ni = 0; ni < 2; ni++) {
        int col = bn * 64 + wc * 32 + ni * 16 + l15;
        float iv = rsqrtf(vp[col] + EPS_) * gp[col];
        inv[ni] = iv;
        sh[ni] = bp[col] - mp[col] * iv;
    }
    #pragma unroll
    for (int mi = 0; mi < 4; mi++)
        #pragma unroll
        for (int ni = 0; ni < 2; ni++) {
            int col = bn * 64 + wc * 32 + ni * 16 + l15;
            #pragma unroll
            for (int r = 0; r < 4; r++) {
                int row = bm * 128 + wr * 64 + mi * 16 + lg * 4 + r;
                float y = fmaxf(fmaf(acc[mi][ni][r], inv[ni], sh[ni]), 0.f);
                if constexpr (OUTBF)
                    ((__bf16*)Cout)[(int64_t)row * N + col] = (__bf16)y;
                else
                    ((float*)Cout)[(int64_t)row * N + col] = y;
            }
        }
}

// ---------------------------------------------------------------------------
// 3b. fp32 GEMM, bias epilogue (W3)
// ---------------------------------------------------------------------------
__global__ __launch_bounds__(256) void gemm_bias_f32(
    const float* __restrict__ A, const float* __restrict__ Bw, float* __restrict__ C,
    int M, int N, int K, const float* __restrict__ bp)
{
    __shared__ float As[32 * 65];
    __shared__ float Bs[32 * 64];
    int tid = threadIdx.x;
    int bm = blockIdx.x, bn = blockIdx.y;
    int tx = tid & 15, ty = tid >> 4;
    float acc[4][4] = {{0.f}};
    const int64_t Abase = (int64_t)bm * 64 * K;

    for (int k0 = 0; k0 < K; k0 += 32) {
        #pragma unroll
        for (int l = 0; l < 8; l++) {
            int idx = tid + 256 * l;
            int mrow = idx >> 5, kk = idx & 31;
            As[kk * 65 + mrow] = A[Abase + (int64_t)mrow * K + k0 + kk];
        }
        #pragma unroll
        for (int l = 0; l < 8; l++) {
            int idx = tid + 256 * l;
            int kk = idx >> 6, nn = idx & 63;
            Bs[kk * 64 + nn] = Bw[(int64_t)(k0 + kk) * N + bn * 64 + nn];
        }
        __syncthreads();
        #pragma unroll
        for (int kk = 0; kk < 32; kk++) {
            float a0 = As[kk * 65 + ty * 4 + 0];
            float a1 = As[kk * 65 + ty * 4 + 1];
            float a2 = As[kk * 65 + ty * 4 + 2];
            float a3 = As[kk * 65 + ty * 4 + 3];
            float4 bv = *(const float4*)&Bs[kk * 64 + tx * 4];
            acc[0][0] = fmaf(a0, bv.x, acc[0][0]); acc[0][1] = fmaf(a0, bv.y, acc[0][1]);
            acc[0][2] = fmaf(a0, bv.z, acc[0][2]); acc[0][3] = fmaf(a0, bv.w, acc[0][3]);
            acc[1][0] = fmaf(a1, bv.x, acc[1][0]); acc[1][1] = fmaf(a1, bv.y, acc[1][1]);
            acc[1][2] = fmaf(a1, bv.z, acc[1][2]); acc[1][3] = fmaf(a1, bv.w, acc[1][3]);
            acc[2][0] = fmaf(a2, bv.x, acc[2][0]); acc[2][1] = fmaf(a2, bv.y, acc[2][1]);
            acc[2][2] = fmaf(a2, bv.z, acc[2][2]); acc[2][3] = fmaf(a2, bv.w, acc[2][3]);
            acc[3][0] = fmaf(a3, bv.x, acc[3][0]); acc[3][1] = fmaf(a3, bv.y, acc[3][1]);
            acc[3][2] = fmaf(a3, bv.z, acc[3][2]); acc[3][3] = fmaf(a3, bv.w, acc[3][3]);
        }
        __syncthreads();
    }
    #pragma unroll
    for (int r = 0; r < 4; r++) {
        int row = bm * 64 + ty * 4 + r;
        float4 y;
        y.x = acc[r][0] + bp[bn * 64 + tx * 4 + 0];
        y.y = acc[r][1] + bp[bn * 64 + tx * 4 + 1];
        y.z = acc[r][2] + bp[bn * 64 + tx * 4 + 2];
        y.w = acc[r][3] + bp[bn * 64 + tx * 4 + 3];
        *(float4*)&C[(int64_t)row * N + bn * 64 + tx * 4] = y;
    }
}

// ---------------------------------------------------------------------------
// 4. FUSED 3-layer attention + final head. One block per batch row, 4 waves.
//    x stays in LDS (bf16, swizzled) between layers; final dot reduced
//    in-block; single f32 output per row.
// ---------------------------------------------------------------------------
__global__ __launch_bounds__(256) void attn3_head_kernel(
    const __bf16* __restrict__ embbf, const __bf16* __restrict__ pkw,
    const float* __restrict__ lng, const float* __restrict__ lnb,
    const float* __restrict__ h3, const float* __restrict__ Wl,
    const float* __restrict__ bl, float* __restrict__ out)
{
    __shared__ __bf16 xs[32 * 128];       // 8 KB, swizzled
    __shared__ __bf16 q_lds[32 * 128];    // 8 KB
    __shared__ __bf16 k_lds[32 * 128];    // 8 KB
    __shared__ __bf16 vt_lds[128 * 32];   // 8 KB
    __shared__ float  r_lds[32 * 128];    // 16 KB
    __shared__ __bf16 p_lds[4 * 512];     // 4 KB (head reduction overlays this)
    __shared__ float  part[32 * 4];       // 512 B

    const int tid = threadIdx.x;
    const int wid = tid >> 6, lane = tid & 63;
    const int l15 = lane & 15, lg = lane >> 4;
    const int b = blockIdx.x;
    const int h = wid >> 1, qh = wid & 1;
    const int q = qh * 16 + l15;

    // ---- stage x (layer-1 input) into swizzled xs
    {
        const __bf16* src = embbf + (int64_t)b * 4096;
        #pragma unroll
        for (int u = 0; u < 2; u++) {
            int c = tid * 2 + u;              // chunk of 8 elems
            int row = c >> 4, slot = c & 15;
            bfv8 v = *(const bfv8*)&src[row * 128 + slot * 8];
            *(bfv8*)&xs[row * 128 + ((slot * 8) ^ ((row & 7) << 3))] = v;
        }
    }
    __syncthreads();

    float head_partial = 0.f;

    for (int l = 0; l < L_; l++) {
        // ---- x fragments from LDS
        bfv8 xf[2][4];
        #pragma unroll
        for (int i = 0; i < 2; i++)
            #pragma unroll
            for (int ks = 0; ks < 4; ks++) {
                int row = i * 16 + l15;
                xf[i][ks] = *(const bfv8*)&xs[row * 128 + ((ks * 32 + lg * 8) ^ ((row & 7) << 3))];
            }

        // ---- projection (64 MFMA per wave)
        const __bf16* W = pkw + (l * 4 + wid) * 16384;
        f32x4 acc[8][2];
        #pragma unroll
        for (int m = 0; m < 8; m++)
            #pragma unroll
            for (int n = 0; n < 2; n++) acc[m][n] = (f32x4){0.f, 0.f, 0.f, 0.f};

        if (wid == 2) {
            for (int m = 0; m < 8; m++) {
                bfv8 wf[4];
                #pragma unroll
                for (int ks = 0; ks < 4; ks++)
                    wf[ks] = *(const bfv8*)(W + ((m * 4 + ks) * 64 + lane) * 8);
                #pragma unroll
                for (int i = 0; i < 2; i++)
                    #pragma unroll
                    for (int ks = 0; ks < 4; ks++)
                        acc[m][i] = mfma16(xf[i][ks], wf[ks], acc[m][i]);
            }
        } else {
            for (int m = 0; m < 8; m++) {
                bfv8 wf[4];
                #pragma unroll
                for (int ks = 0; ks < 4; ks++)
                    wf[ks] = *(const bfv8*)(W + ((m * 4 + ks) * 64 + lane) * 8);
                #pragma unroll
                for (int i = 0; i < 2; i++)
                    #pragma unroll
                    for (int ks = 0; ks < 4; ks++)
                        acc[m][i] = mfma16(wf[ks], xf[i][ks], acc[m][i]);
            }
        }

        // ---- store projections to LDS
        if (wid == 0) {
            #pragma unroll
            for (int m = 0; m < 8; m++)
                #pragma unroll
                for (int n = 0; n < 2; n++) {
                    int qq = n * 16 + l15, j = m * 16 + lg * 4;
                    bfv4 v4;
                    #pragma unroll
                    for (int r = 0; r < 4; r++) v4[r] = (__bf16)(acc[m][n][r] * 0.125f);
                    *(bfv4*)&q_lds[qq * 128 + (j ^ ((qq & 7) << 3))] = v4;
                }
        } else if (wid == 1) {
            #pragma unroll
            for (int m = 0; m < 8; m++)
                #pragma unroll
                for (int n = 0; n < 2; n++) {
                    int qq = n * 16 + l15, j = m * 16 + lg * 4;
                    bfv4 v4;
                    #pragma unroll
                    for (int r = 0; r < 4; r++) v4[r] = (__bf16)acc[m][n][r];
                    *(bfv4*)&k_lds[qq * 128 + (j ^ ((qq & 7) << 3))] = v4;
                }
        } else if (wid == 2) {
            #pragma unroll
            for (int m = 0; m < 8; m++)
                #pragma unroll
                for (int i = 0; i < 2; i++) {
                    int d = m * 16 + l15, key = i * 16 + lg * 4;
                    bfv4 v4;
                    #pragma unroll
                    for (int r = 0; r < 4; r++) v4[r] = (__bf16)acc[m][i][r];
                    *(bfv4*)&vt_lds[d * 32 + (key ^ (((d >> 1) & 3) << 3))] = v4;
                }
        } else {
            #pragma unroll
            for (int m = 0; m < 8; m++)
                #pragma unroll
                for (int n = 0; n < 2; n++) {
                    int qq = n * 16 + l15, j = m * 16 + lg * 4;
                    *(f32x4*)&r_lds[qq * 128 + (j ^ ((qq & 7) << 2))] = acc[m][n];
                }
        }
        __syncthreads();

        // ---- scores S^T = k @ q^T per (head, query-half)
        f32x4 sc2[2] = {(f32x4){0.f, 0.f, 0.f, 0.f}, (f32x4){0.f, 0.f, 0.f, 0.f}};
        #pragma unroll
        for (int ks = 0; ks < 2; ks++) {
            int d = h * 64 + ks * 32 + lg * 8;
            bfv8 qb = *(const bfv8*)&q_lds[q * 128 + (d ^ ((q & 7) << 3))];
            #pragma unroll
            for (int km = 0; km < 2; km++) {
                int key = km * 16 + l15;
                bfv8 kb = *(const bfv8*)&k_lds[key * 128 + (d ^ ((key & 7) << 3))];
                sc2[km] = mfma16(kb, qb, sc2[km]);
            }
        }

        // ---- softmax over 32 keys
        float mx = -1e30f;
        #pragma unroll
        for (int km = 0; km < 2; km++)
            #pragma unroll
            for (int r = 0; r < 4; r++) mx = fmaxf(mx, sc2[km][r]);
        mx = fmaxf(mx, __shfl_xor(mx, 16));
        mx = fmaxf(mx, __shfl_xor(mx, 32));
        float pv[2][4];
        float sum = 0.f;
        #pragma unroll
        for (int km = 0; km < 2; km++)
            #pragma unroll
            for (int r = 0; r < 4; r++) {
                float e = __expf(sc2[km][r] - mx);
                pv[km][r] = e; sum += e;
            }
        sum += __shfl_xor(sum, 16);
        sum += __shfl_xor(sum, 32);
        float inv = 1.f / sum;

        // ---- P^T -> wave-private p_lds
        __bf16* pw = p_lds + wid * 512;
        #pragma unroll
        for (int km = 0; km < 2; km++) {
            int key = km * 16 + lg * 4;
            bfv4 v4;
            #pragma unroll
            for (int r = 0; r < 4; r++) v4[r] = (__bf16)(pv[km][r] * inv);
            *(bfv4*)&pw[l15 * 32 + (key ^ (((l15 >> 1) & 3) << 3))] = v4;
        }

        // ---- PV: o^T = v^T @ P^T
        bfv8 pb = *(const bfv8*)&pw[l15 * 32 + ((lg * 8) ^ (((l15 >> 1) & 3) << 3))];
        f32x4 o[4];
        #pragma unroll
        for (int dm = 0; dm < 4; dm++) {
            int d = h * 64 + dm * 16 + l15;
            bfv8 va = *(const bfv8*)&vt_lds[d * 32 + ((lg * 8) ^ (((d >> 1) & 3) << 3))];
            o[dm] = mfma16(va, pb, (f32x4){0.f, 0.f, 0.f, 0.f});
        }

        // ---- relu(o + res), partial LN stats
        float yv[4][4];
        float s1 = 0.f, s2 = 0.f;
        #pragma unroll
        for (int dm = 0; dm < 4; dm++) {
            int j = h * 64 + dm * 16 + lg * 4;
            f32x4 r4 = *(const f32x4*)&r_lds[q * 128 + (j ^ ((q & 7) << 2))];
            #pragma unroll
            for (int r = 0; r < 4; r++) {
                float v = fmaxf(o[dm][r] + r4[r], 0.f);
                yv[dm][r] = v;
                s1 += v; s2 += v * v;
            }
        }
        s1 += __shfl_xor(s1, 16); s1 += __shfl_xor(s1, 32);
        s2 += __shfl_xor(s2, 16); s2 += __shfl_xor(s2, 32);
        if (lg == 0) { part[q * 4 + h * 2] = s1; part[q * 4 + h * 2 + 1] = s2; }
        __syncthreads();   // also guarantees all waves done with q/k/vt/r/p

        // ---- layernorm
        f32x4 pt = *(const f32x4*)&part[q * 4];
        float mean = (pt[0] + pt[2]) * (1.f / 128.f);
        float var  = (pt[1] + pt[3]) * (1.f / 128.f) - mean * mean;
        float rstd = rsqrtf(var + EPS_);
        const float* lgp = lng + l * HD_;
        const float* lbp = lnb + l * HD_;

        if (l < L_ - 1) {
            // write next-layer x (bf16) into xs, swizzled
            #pragma unroll
            for (int dm = 0; dm < 4; dm++) {
                int j = h * 64 + dm * 16 + lg * 4;
                float4 g  = *(const float4*)(lgp + j);
                float4 bb = *(const float4*)(lbp + j);
                bfv4 y;
                y[0] = (__bf16)((yv[dm][0] - mean) * rstd * g.x + bb.x);
                y[1] = (__bf16)((yv[dm][1] - mean) * rstd * g.y + bb.y);
                y[2] = (__bf16)((yv[dm][2] - mean) * rstd * g.z + bb.z);
                y[3] = (__bf16)((yv[dm][3] - mean) * rstd * g.w + bb.w);
                *(bfv4*)&xs[q * 128 + (j ^ ((q & 7) << 3))] = y;
            }
            __syncthreads();   // xs visible before next layer's fragment reads
        } else {
            // final head: partial dot of f32 LN output with W_last
            #pragma unroll
            for (int dm = 0; dm < 4; dm++) {
                int j = h * 64 + dm * 16 + lg * 4;
                float4 g  = *(const float4*)(lgp + j);
                float4 bb = *(const float4*)(lbp + j);
                float4 w  = *(const float4*)(Wl + q * HD_ + j);
                head_partial = fmaf((yv[dm][0] - mean) * rstd * g.x + bb.x, w.x, head_partial);
                head_partial = fmaf((yv[dm][1] - mean) * rstd * g.y + bb.y, w.y, head_partial);
                head_partial = fmaf((yv[dm][2] - mean) * rstd * g.z + bb.z, w.z, head_partial);
                head_partial = fmaf((yv[dm][3] - mean) * rstd * g.w + bb.w, w.w, head_partial);
            }
        }
    }

    // ---- block reduction of head partials (overlay red on p_lds; p is dead)
    float* red = (float*)p_lds;
    red[tid] = head_partial;
    __syncthreads();
    if (wid == 0) {
        float s = red[lane] + red[lane + 64] + red[lane + 128] + red[lane + 192];
        s += h3[(int64_t)b * 128 + lane]      * Wl[4096 + lane];
        s += h3[(int64_t)b * 128 + 64 + lane] * Wl[4096 + 64 + lane];
        #pragma unroll
        for (int off = 32; off; off >>= 1) s += __shfl_down(s, off);
        if (lane == 0) out[b] = 1.f / (1.f + __expf(-(s + bl[0])));
    }
}

// ---------------------------------------------------------------------------
extern "C" void kernel_launch(void* const* d_in, const int* in_sizes, int n_in,
                              void* d_out, int out_size, void* d_ws, size_t ws_size,
                              hipStream_t stream)
{
    const int*   tokens       = (const int*)  d_in[0];
    const int*   field_ids    = (const int*)  d_in[1];
    const float* word_emb     = (const float*)d_in[2];
    const float* W_tok        = (const float*)d_in[3];
    const float* field_tables = (const float*)d_in[4];
    const float* Wq           = (const float*)d_in[5];
    const float* Wk           = (const float*)d_in[6];
    const float* Wv           = (const float*)d_in[7];
    const float* Wres         = (const float*)d_in[8];
    const float* ln_g         = (const float*)d_in[9];
    const float* ln_b         = (const float*)d_in[10];
    const float* dnn_W1       = (const float*)d_in[11];
    const float* bn1_g        = (const float*)d_in[12];
    const float* bn1_b        = (const float*)d_in[13];
    const float* bn1_m        = (const float*)d_in[14];
    const float* bn1_v        = (const float*)d_in[15];
    const float* dnn_W2       = (const float*)d_in[16];
    const float* bn2_g        = (const float*)d_in[17];
    const float* bn2_b        = (const float*)d_in[18];
    const float* bn2_m        = (const float*)d_in[19];
    const float* bn2_v        = (const float*)d_in[20];
    const float* dnn_W3       = (const float*)d_in[21];
    const float* dnn_b3       = (const float*)d_in[22];
    const float* W_last       = (const float*)d_in[23];
    const float* b_last       = (const float*)d_in[24];
    float* out = (float*)d_out;

    const int64_t embN = (int64_t)B_ * F_ * E_;          // 16,777,216
    __bf16* embbf = (__bf16*)d_ws;                        // 32 MB
    float*  h3    = (float*)(embbf + embN);               // 2 MB
    __bf16* pkw   = (__bf16*)(h3 + (int64_t)B_ * 128);    // 384 KB
    __bf16* W1t   = pkw + 12 * 16384;                     // 8 MB
    __bf16* W2t   = W1t + (int64_t)1024 * 4096;           // 1 MB
    __bf16* h1bf  = W2t + (int64_t)512 * 1024;            // 8 MB
    float*  h2f   = (float*)(h1bf + (int64_t)B_ * 1024);  // 8 MB

    // weight packing
    pack_weights_kernel<<<dim3(12, 8), 256, 0, stream>>>(Wq, Wk, Wv, Wres, pkw);
    transpose_pack_kernel<<<dim3(64, 16), 256, 0, stream>>>(dnn_W1, W1t, 4096, 1024);
    transpose_pack_kernel<<<dim3(16, 8), 256, 0, stream>>>(dnn_W2, W2t, 1024, 512);

    // embeddings (bf16)
    tok_embed_kernel<<<B_, 128, 0, stream>>>(tokens, word_emb, W_tok, embbf);
    field_gather_kernel<<<(B_ * 31 * 32) / 256, 256, 0, stream>>>(field_ids, field_tables, embbf);

    // DNN tower
    gemm_bt_bf16_bn<1><<<dim3(32, 16), 256, 0, stream>>>(
        embbf, W1t, h1bf, B_, 1024, 4096, bn1_g, bn1_b, bn1_m, bn1_v);
    gemm_bt_bf16_bn<0><<<dim3(32, 8), 256, 0, stream>>>(
        h1bf, W2t, h2f, B_, 512, 1024, bn2_g, bn2_b, bn2_m, bn2_v);
    gemm_bias_f32<<<dim3(64, 2), 256, 0, stream>>>(
        h2f, dnn_W3, h3, B_, 128, 512, dnn_b3);

    // fused attention stack + head
    attn3_head_kernel<<<B_, 256, 0, stream>>>(
        embbf, pkw, ln_g, ln_b, h3, W_last, b_last, out);
}

// Round 5
// 283.198 us; speedup vs baseline: 8.6222x; 1.0692x over previous
//
#include <hip/hip_runtime.h>
#include <hip/hip_bf16.h>
#include <cstdint>

#define B_  4096
#define T_  20
#define F_  32
#define E_  128
#define H_  2
#define D_  64
#define L_  3
#define HD_ 128
#define EPS_ 1e-5f

typedef __bf16 bfv8 __attribute__((ext_vector_type(8)));
typedef __bf16 bfv4 __attribute__((ext_vector_type(4)));
typedef float  f32x4 __attribute__((ext_vector_type(4)));

__device__ __forceinline__ f32x4 mfma16(bfv8 a, bfv8 b, f32x4 c) {
    return __builtin_amdgcn_mfma_f32_16x16x32_bf16(a, b, c, 0, 0, 0);
}

__device__ __forceinline__ void gload16(const __bf16* g, __bf16* l) {
    __builtin_amdgcn_global_load_lds(
        (const __attribute__((address_space(1))) void*)(g),
        (__attribute__((address_space(3))) void*)(l),
        16, 0, 0);
}

// ---------------------------------------------------------------------------
// 0a. pack attention weights into MFMA-fragment-ready bf16
// ---------------------------------------------------------------------------
__global__ __launch_bounds__(256) void pack_weights_kernel(
    const float* __restrict__ Wq, const float* __restrict__ Wk,
    const float* __restrict__ Wv, const float* __restrict__ Wres,
    __bf16* __restrict__ out)
{
    int mi = blockIdx.x;   // l*4 + p
    int tile = blockIdx.y; // 0..7
    int l = mi >> 2, p = mi & 3;
    const float* Wb = (p == 0 ? Wq : p == 1 ? Wk : p == 2 ? Wv : Wres) + l * 16384;
    int tid = threadIdx.x;
    int ks = tid >> 6, lane = tid & 63;
    int l15 = lane & 15, lgg = lane >> 4;
    const float* src = Wb + (ks * 32 + lgg * 8) * HD_ + tile * 16 + l15;
    __bf16* dst = out + (int64_t)mi * 16384 + ((tile * 4 + ks) * 64 + lane) * 8;
    #pragma unroll
    for (int t = 0; t < 8; t++) dst[t] = (__bf16)src[t * HD_];
}

// ---------------------------------------------------------------------------
// 0b. transpose-pack f32 [K][N] -> bf16 [N][K]
// ---------------------------------------------------------------------------
__global__ __launch_bounds__(256) void transpose_pack_kernel(
    const float* __restrict__ in, __bf16* __restrict__ out, int K, int N)
{
    __shared__ float t[64][65];
    int k0 = blockIdx.x * 64, n0 = blockIdx.y * 64;
    int r = threadIdx.x >> 4, c = (threadIdx.x & 15) * 4;
    for (int rr = r; rr < 64; rr += 16) {
        float4 v = *(const float4*)&in[(int64_t)(k0 + rr) * N + n0 + c];
        t[rr][c] = v.x; t[rr][c + 1] = v.y; t[rr][c + 2] = v.z; t[rr][c + 3] = v.w;
    }
    __syncthreads();
    for (int rr = r; rr < 64; rr += 16) {
        bfv4 o;
        o[0] = (__bf16)t[c + 0][rr];
        o[1] = (__bf16)t[c + 1][rr];
        o[2] = (__bf16)t[c + 2][rr];
        o[3] = (__bf16)t[c + 3][rr];
        *(bfv4*)&out[(int64_t)(n0 + rr) * K + k0 + c] = o;
    }
}

// ---------------------------------------------------------------------------
// 1. token embedding -> bf16 emb row (field 0)
// ---------------------------------------------------------------------------
__global__ __launch_bounds__(128) void tok_embed_kernel(
    const int* __restrict__ tokens, const float* __restrict__ word_emb,
    const float* __restrict__ W_tok, __bf16* __restrict__ embbf)
{
    int b = blockIdx.x;
    int tid = threadIdx.x;
    __shared__ float m[300];
    float a0 = 0.f, a1 = 0.f, a2 = 0.f;
    const int* tb = tokens + b * T_;
    for (int t = 0; t < T_; t++) {
        const float* row = word_emb + (int64_t)tb[t] * 300;
        a0 += row[tid];
        a1 += row[tid + 128];
        if (tid < 44) a2 += row[tid + 256];
    }
    m[tid]       = a0 * (1.f / T_);
    m[tid + 128] = a1 * (1.f / T_);
    if (tid < 44) m[tid + 256] = a2 * (1.f / T_);
    __syncthreads();
    float s = 0.f;
    for (int e = 0; e < 300; e++) s = fmaf(m[e], W_tok[e * E_ + tid], s);
    embbf[(int64_t)b * (F_ * E_) + tid] = (__bf16)s;
}

// ---------------------------------------------------------------------------
// 2. field embedding gather -> bf16
// ---------------------------------------------------------------------------
__global__ __launch_bounds__(256) void field_gather_kernel(
    const int* __restrict__ field_ids, const float* __restrict__ field_tables,
    __bf16* __restrict__ embbf)
{
    int64_t idx = (int64_t)blockIdx.x * blockDim.x + threadIdx.x;
    if (idx >= (int64_t)B_ * 31 * 32) return;
    int c = (int)(idx & 31);
    int64_t tmp = idx >> 5;
    int f = (int)(tmp % 31);
    int b = (int)(tmp / 31);
    int id = field_ids[b * 31 + f];
    const float4* src = (const float4*)field_tables;
    float4 val = src[(int64_t)(f * 1000 + id) * 32 + c];
    bfv4 o;
    o[0] = (__bf16)val.x; o[1] = (__bf16)val.y;
    o[2] = (__bf16)val.z; o[3] = (__bf16)val.w;
    *(bfv4*)&embbf[(int64_t)b * 4096 + (1 + f) * 128 + c * 4] = o;
}

// ---------------------------------------------------------------------------
// 3a. bf16 MFMA GEMM, B^T operand, fused BN+ReLU epilogue. BK=64.
//     BM=128, BN=64, 256 threads / 4 waves, wave tile 64x32, 16 MFMA/K-step.
//     8-slot XOR swizzle (slot ^= row&7), both sides.
// ---------------------------------------------------------------------------
template <int OUTBF>
__global__ __launch_bounds__(256) void gemm_bt_bf16_bn(
    const __bf16* __restrict__ A, const __bf16* __restrict__ Bt,
    void* __restrict__ Cout, int M, int N, int K,
    const float* __restrict__ gp, const float* __restrict__ bp,
    const float* __restrict__ mp, const float* __restrict__ vp)
{
    __shared__ __bf16 As[128 * 64];   // 16 KB
    __shared__ __bf16 Bs[64 * 64];    // 8 KB
    const int tid = threadIdx.x;
    const int wid = tid >> 6, lane = tid & 63;
    const int l15 = lane & 15, lg = lane >> 4;
    const int wr = wid >> 1, wc = wid & 1;
    const int bm = blockIdx.x, bn = blockIdx.y;

    // staging: per wave 4 A-gloads (rows wid*32..+31) + 2 B-gloads (rows wid*16..+15)
    const int srow = lane >> 3, sp = lane & 7;
    const __bf16* Ag[4]; const __bf16* Bg[2];
    __bf16* Ad[4]; __bf16* Bd[2];
    #pragma unroll
    for (int ga = 0; ga < 4; ga++) {
        int row = wid * 32 + ga * 8 + srow;
        int slot = sp ^ (row & 7);
        Ag[ga] = A + (int64_t)(bm * 128 + row) * K + slot * 8;
        Ad[ga] = &As[(wid * 32 + ga * 8) * 64];
    }
    #pragma unroll
    for (int gb = 0; gb < 2; gb++) {
        int row = wid * 16 + gb * 8 + srow;
        int slot = sp ^ (row & 7);
        Bg[gb] = Bt + (int64_t)(bn * 64 + row) * K + slot * 8;
        Bd[gb] = &Bs[(wid * 16 + gb * 8) * 64];
    }

    // fragment read offsets (swizzled), per ks in {0,1}
    int ar[2][4], br2[2][2];
    #pragma unroll
    for (int ks = 0; ks < 2; ks++) {
        #pragma unroll
        for (int mi = 0; mi < 4; mi++) {
            int row = wr * 64 + mi * 16 + l15;
            ar[ks][mi] = row * 64 + (((ks * 4 + lg) ^ (row & 7)) * 8);
        }
        #pragma unroll
        for (int ni = 0; ni < 2; ni++) {
            int row = wc * 32 + ni * 16 + l15;
            br2[ks][ni] = row * 64 + (((ks * 4 + lg) ^ (row & 7)) * 8);
        }
    }

    f32x4 acc[4][2];
    #pragma unroll
    for (int mi = 0; mi < 4; mi++)
        #pragma unroll
        for (int ni = 0; ni < 2; ni++) acc[mi][ni] = (f32x4){0.f, 0.f, 0.f, 0.f};

    for (int k0 = 0; k0 < K; k0 += 64) {
        #pragma unroll
        for (int ga = 0; ga < 4; ga++) gload16(Ag[ga] + k0, Ad[ga]);
        #pragma unroll
        for (int gb = 0; gb < 2; gb++) gload16(Bg[gb] + k0, Bd[gb]);
        __syncthreads();
        #pragma unroll
        for (int ks = 0; ks < 2; ks++) {
            bfv8 af[4], bf2[2];
            #pragma unroll
            for (int mi = 0; mi < 4; mi++) af[mi] = *(const bfv8*)&As[ar[ks][mi]];
            #pragma unroll
            for (int ni = 0; ni < 2; ni++) bf2[ni] = *(const bfv8*)&Bs[br2[ks][ni]];
            #pragma unroll
            for (int mi = 0; mi < 4; mi++)
                #pragma unroll
                for (int ni = 0; ni < 2; ni++)
                    acc[mi][ni] = mfma16(af[mi], bf2[ni], acc[mi][ni]);
        }
        __syncthreads();
    }

    float inv[2], sh[2];
    #pragma unroll
    for (int ni = 0; ni < 2; ni++) {
        int col = bn * 64 + wc * 32 + ni * 16 + l15;
        float iv = rsqrtf(vp[col] + EPS_) * gp[col];
        inv[ni] = iv;
        sh[ni] = bp[col] - mp[col] * iv;
    }
    #pragma unroll
    for (int mi = 0; mi < 4; mi++)
        #pragma unroll
        for (int ni = 0; ni < 2; ni++) {
            int col = bn * 64 + wc * 32 + ni * 16 + l15;
            #pragma unroll
            for (int r = 0; r < 4; r++) {
                int row = bm * 128 + wr * 64 + mi * 16 + lg * 4 + r;
                float y = fmaxf(fmaf(acc[mi][ni][r], inv[ni], sh[ni]), 0.f);
                if constexpr (OUTBF)
                    ((__bf16*)Cout)[(int64_t)row * N + col] = (__bf16)y;
                else
                    ((float*)Cout)[(int64_t)row * N + col] = y;
            }
        }
}

// ---------------------------------------------------------------------------
// 3b. fp32 GEMM, bias epilogue (W3)
// ---------------------------------------------------------------------------
__global__ __launch_bounds__(256) void gemm_bias_f32(
    const float* __restrict__ A, const float* __restrict__ Bw, float* __restrict__ C,
    int M, int N, int K, const float* __restrict__ bp)
{
    __shared__ float As[32 * 65];
    __shared__ float Bs[32 * 64];
    int tid = threadIdx.x;
    int bm = blockIdx.x, bn = blockIdx.y;
    int tx = tid & 15, ty = tid >> 4;
    float acc[4][4] = {{0.f}};
    const int64_t Abase = (int64_t)bm * 64 * K;

    for (int k0 = 0; k0 < K; k0 += 32) {
        #pragma unroll
        for (int l = 0; l < 8; l++) {
            int idx = tid + 256 * l;
            int mrow = idx >> 5, kk = idx & 31;
            As[kk * 65 + mrow] = A[Abase + (int64_t)mrow * K + k0 + kk];
        }
        #pragma unroll
        for (int l = 0; l < 8; l++) {
            int idx = tid + 256 * l;
            int kk = idx >> 6, nn = idx & 63;
            Bs[kk * 64 + nn] = Bw[(int64_t)(k0 + kk) * N + bn * 64 + nn];
        }
        __syncthreads();
        #pragma unroll
        for (int kk = 0; kk < 32; kk++) {
            float a0 = As[kk * 65 + ty * 4 + 0];
            float a1 = As[kk * 65 + ty * 4 + 1];
            float a2 = As[kk * 65 + ty * 4 + 2];
            float a3 = As[kk * 65 + ty * 4 + 3];
            float4 bv = *(const float4*)&Bs[kk * 64 + tx * 4];
            acc[0][0] = fmaf(a0, bv.x, acc[0][0]); acc[0][1] = fmaf(a0, bv.y, acc[0][1]);
            acc[0][2] = fmaf(a0, bv.z, acc[0][2]); acc[0][3] = fmaf(a0, bv.w, acc[0][3]);
            acc[1][0] = fmaf(a1, bv.x, acc[1][0]); acc[1][1] = fmaf(a1, bv.y, acc[1][1]);
            acc[1][2] = fmaf(a1, bv.z, acc[1][2]); acc[1][3] = fmaf(a1, bv.w, acc[1][3]);
            acc[2][0] = fmaf(a2, bv.x, acc[2][0]); acc[2][1] = fmaf(a2, bv.y, acc[2][1]);
            acc[2][2] = fmaf(a2, bv.z, acc[2][2]); acc[2][3] = fmaf(a2, bv.w, acc[2][3]);
            acc[3][0] = fmaf(a3, bv.x, acc[3][0]); acc[3][1] = fmaf(a3, bv.y, acc[3][1]);
            acc[3][2] = fmaf(a3, bv.z, acc[3][2]); acc[3][3] = fmaf(a3, bv.w, acc[3][3]);
        }
        __syncthreads();
    }
    #pragma unroll
    for (int r = 0; r < 4; r++) {
        int row = bm * 64 + ty * 4 + r;
        float4 y;
        y.x = acc[r][0] + bp[bn * 64 + tx * 4 + 0];
        y.y = acc[r][1] + bp[bn * 64 + tx * 4 + 1];
        y.z = acc[r][2] + bp[bn * 64 + tx * 4 + 2];
        y.w = acc[r][3] + bp[bn * 64 + tx * 4 + 3];
        *(float4*)&C[(int64_t)row * N + bn * 64 + tx * 4] = y;
    }
}

// ---------------------------------------------------------------------------
// 4. FUSED 3-layer attention + head, 2 batch rows per block, 512 threads.
//    Projection: wave=(mat=wid&3, half=wid>>2): loads HALF of one weight
//    matrix (m-tiles half*4..+3) and applies it to 4 x-row-tiles (2 rows x
//    2 field-halves) -> per-row weight traffic halved vs round 4.
//    Attention: wave=(row=wid>>2, h=(wid>>1)&1, qh=wid&1).
// ---------------------------------------------------------------------------
__global__ __launch_bounds__(512, 2) void attn3_head_kernel(
    const __bf16* __restrict__ embbf, const __bf16* __restrict__ pkw,
    const float* __restrict__ lng, const float* __restrict__ lnb,
    const float* __restrict__ h3, const float* __restrict__ Wl,
    const float* __restrict__ bl, float* __restrict__ out)
{
    __shared__ __bf16 xs[2][32 * 128];     // 16 KB, swizzled
    __shared__ __bf16 q_lds[2][32 * 128];  // 16 KB
    __shared__ __bf16 k_lds[2][32 * 128];  // 16 KB
    __shared__ __bf16 vt_lds[2][128 * 32]; // 16 KB
    __shared__ float  r_lds[2][32 * 128];  // 32 KB
    __shared__ __bf16 p_lds[8 * 512];      // 8 KB (overlaid by red[512] f32)
    __shared__ float  part[2][128];        // 1 KB

    const int tid = threadIdx.x;
    const int wid = tid >> 6, lane = tid & 63;
    const int l15 = lane & 15, lg = lane >> 4;
    const int mat = wid & 3, half = wid >> 2;            // projection role
    const int arow = wid >> 2, h = (wid >> 1) & 1, qh = wid & 1; // attn role
    const int q = qh * 16 + l15;

    // ---- stage x for both rows into swizzled xs
    {
        const __bf16* src = embbf + (int64_t)blockIdx.x * 8192;
        #pragma unroll
        for (int u = 0; u < 2; u++) {
            int c = tid * 2 + u;                 // 0..1023 chunks of 8 bf16
            int brow = c >> 9, fld = (c >> 4) & 31, slot = c & 15;
            bfv8 v = *(const bfv8*)&src[brow * 4096 + fld * 128 + slot * 8];
            *(bfv8*)&xs[brow][fld * 128 + ((slot * 8) ^ ((fld & 7) << 3))] = v;
        }
    }
    __syncthreads();

    float head_partial = 0.f;

    for (int l = 0; l < L_; l++) {
        // ---- x fragments: i = brow*2 + fieldhalf
        bfv8 xf[4][4];
        #pragma unroll
        for (int i = 0; i < 4; i++)
            #pragma unroll
            for (int ks = 0; ks < 4; ks++) {
                int br = i >> 1, fld = (i & 1) * 16 + l15;
                xf[i][ks] = *(const bfv8*)&xs[br][fld * 128 + ((ks * 32 + lg * 8) ^ ((fld & 7) << 3))];
            }

        // ---- projection: 4 m-tiles x 4 i-tiles x 4 ks = 64 MFMA
        const __bf16* W = pkw + (l * 4 + mat) * 16384;
        f32x4 acc[4][4];   // [mm][i]
        #pragma unroll
        for (int mm = 0; mm < 4; mm++)
            #pragma unroll
            for (int i = 0; i < 4; i++) acc[mm][i] = (f32x4){0.f, 0.f, 0.f, 0.f};

        if (mat == 2) {
            #pragma unroll
            for (int mm = 0; mm < 4; mm++) {
                int m = half * 4 + mm;
                bfv8 wf[4];
                #pragma unroll
                for (int ks = 0; ks < 4; ks++)
                    wf[ks] = *(const bfv8*)(W + ((m * 4 + ks) * 64 + lane) * 8);
                #pragma unroll
                for (int i = 0; i < 4; i++)
                    #pragma unroll
                    for (int ks = 0; ks < 4; ks++)
                        acc[mm][i] = mfma16(xf[i][ks], wf[ks], acc[mm][i]);
            }
        } else {
            #pragma unroll
            for (int mm = 0; mm < 4; mm++) {
                int m = half * 4 + mm;
                bfv8 wf[4];
                #pragma unroll
                for (int ks = 0; ks < 4; ks++)
                    wf[ks] = *(const bfv8*)(W + ((m * 4 + ks) * 64 + lane) * 8);
                #pragma unroll
                for (int i = 0; i < 4; i++)
                    #pragma unroll
                    for (int ks = 0; ks < 4; ks++)
                        acc[mm][i] = mfma16(wf[ks], xf[i][ks], acc[mm][i]);
            }
        }

        // ---- store projections to LDS
        if (mat == 0) {
            #pragma unroll
            for (int mm = 0; mm < 4; mm++)
                #pragma unroll
                for (int i = 0; i < 4; i++) {
                    int br = i >> 1, fld = (i & 1) * 16 + l15;
                    int j = (half * 4 + mm) * 16 + lg * 4;
                    bfv4 v4;
                    #pragma unroll
                    for (int r = 0; r < 4; r++) v4[r] = (__bf16)(acc[mm][i][r] * 0.125f);
                    *(bfv4*)&q_lds[br][fld * 128 + (j ^ ((fld & 7) << 3))] = v4;
                }
        } else if (mat == 1) {
            #pragma unroll
            for (int mm = 0; mm < 4; mm++)
                #pragma unroll
                for (int i = 0; i < 4; i++) {
                    int br = i >> 1, fld = (i & 1) * 16 + l15;
                    int j = (half * 4 + mm) * 16 + lg * 4;
                    bfv4 v4;
                    #pragma unroll
                    for (int r = 0; r < 4; r++) v4[r] = (__bf16)acc[mm][i][r];
                    *(bfv4*)&k_lds[br][fld * 128 + (j ^ ((fld & 7) << 3))] = v4;
                }
        } else if (mat == 2) {
            #pragma unroll
            for (int mm = 0; mm < 4; mm++)
                #pragma unroll
                for (int i = 0; i < 4; i++) {
                    int br = i >> 1;
                    int d = (half * 4 + mm) * 16 + l15;
                    int key = (i & 1) * 16 + lg * 4;
                    bfv4 v4;
                    #pragma unroll
                    for (int r = 0; r < 4; r++) v4[r] = (__bf16)acc[mm][i][r];
                    *(bfv4*)&vt_lds[br][d * 32 + (key ^ (((d >> 1) & 3) << 3))] = v4;
                }
        } else {
            #pragma unroll
            for (int mm = 0; mm < 4; mm++)
                #pragma unroll
                for (int i = 0; i < 4; i++) {
                    int br = i >> 1, fld = (i & 1) * 16 + l15;
                    int j = (half * 4 + mm) * 16 + lg * 4;
                    *(f32x4*)&r_lds[br][fld * 128 + (j ^ ((fld & 7) << 2))] = acc[mm][i];
                }
        }
        __syncthreads();

        // ---- scores S^T = k @ q^T for (arow, h, qh)
        f32x4 sc2[2] = {(f32x4){0.f, 0.f, 0.f, 0.f}, (f32x4){0.f, 0.f, 0.f, 0.f}};
        #pragma unroll
        for (int ks = 0; ks < 2; ks++) {
            int d = h * 64 + ks * 32 + lg * 8;
            bfv8 qb = *(const bfv8*)&q_lds[arow][q * 128 + (d ^ ((q & 7) << 3))];
            #pragma unroll
            for (int km = 0; km < 2; km++) {
                int key = km * 16 + l15;
                bfv8 kb = *(const bfv8*)&k_lds[arow][key * 128 + (d ^ ((key & 7) << 3))];
                sc2[km] = mfma16(kb, qb, sc2[km]);
            }
        }

        // ---- softmax over 32 keys
        float mx = -1e30f;
        #pragma unroll
        for (int km = 0; km < 2; km++)
            #pragma unroll
            for (int r = 0; r < 4; r++) mx = fmaxf(mx, sc2[km][r]);
        mx = fmaxf(mx, __shfl_xor(mx, 16));
        mx = fmaxf(mx, __shfl_xor(mx, 32));
        float pv[2][4];
        float sum = 0.f;
        #pragma unroll
        for (int km = 0; km < 2; km++)
            #pragma unroll
            for (int r = 0; r < 4; r++) {
                float e = __expf(sc2[km][r] - mx);
                pv[km][r] = e; sum += e;
            }
        sum += __shfl_xor(sum, 16);
        sum += __shfl_xor(sum, 32);
        float inv = 1.f / sum;

        // ---- P^T -> wave-private p_lds
        __bf16* pw = p_lds + wid * 512;
        #pragma unroll
        for (int km = 0; km < 2; km++) {
            int key = km * 16 + lg * 4;
            bfv4 v4;
            #pragma unroll
            for (int r = 0; r < 4; r++) v4[r] = (__bf16)(pv[km][r] * inv);
            *(bfv4*)&pw[l15 * 32 + (key ^ (((l15 >> 1) & 3) << 3))] = v4;
        }

        // ---- PV: o^T = v^T @ P^T
        bfv8 pb = *(const bfv8*)&pw[l15 * 32 + ((lg * 8) ^ (((l15 >> 1) & 3) << 3))];
        f32x4 o[4];
        #pragma unroll
        for (int dm = 0; dm < 4; dm++) {
            int d = h * 64 + dm * 16 + l15;
            bfv8 va = *(const bfv8*)&vt_lds[arow][d * 32 + ((lg * 8) ^ (((d >> 1) & 3) << 3))];
            o[dm] = mfma16(va, pb, (f32x4){0.f, 0.f, 0.f, 0.f});
        }

        // ---- relu(o + res), partial LN stats
        float yv[4][4];
        float s1 = 0.f, s2 = 0.f;
        #pragma unroll
        for (int dm = 0; dm < 4; dm++) {
            int j = h * 64 + dm * 16 + lg * 4;
            f32x4 r4 = *(const f32x4*)&r_lds[arow][q * 128 + (j ^ ((q & 7) << 2))];
            #pragma unroll
            for (int r = 0; r < 4; r++) {
                float v = fmaxf(o[dm][r] + r4[r], 0.f);
                yv[dm][r] = v;
                s1 += v; s2 += v * v;
            }
        }
        s1 += __shfl_xor(s1, 16); s1 += __shfl_xor(s1, 32);
        s2 += __shfl_xor(s2, 16); s2 += __shfl_xor(s2, 32);
        if (lg == 0) { part[arow][q * 4 + h * 2] = s1; part[arow][q * 4 + h * 2 + 1] = s2; }
        __syncthreads();

        // ---- layernorm
        f32x4 pt = *(const f32x4*)&part[arow][q * 4];
        float mean = (pt[0] + pt[2]) * (1.f / 128.f);
        float var  = (pt[1] + pt[3]) * (1.f / 128.f) - mean * mean;
        float rstd = rsqrtf(var + EPS_);
        const float* lgp = lng + l * HD_;
        const float* lbp = lnb + l * HD_;

        if (l < L_ - 1) {
            #pragma unroll
            for (int dm = 0; dm < 4; dm++) {
                int j = h * 64 + dm * 16 + lg * 4;
                float4 g  = *(const float4*)(lgp + j);
                float4 bb = *(const float4*)(lbp + j);
                bfv4 y;
                y[0] = (__bf16)((yv[dm][0] - mean) * rstd * g.x + bb.x);
                y[1] = (__bf16)((yv[dm][1] - mean) * rstd * g.y + bb.y);
                y[2] = (__bf16)((yv[dm][2] - mean) * rstd * g.z + bb.z);
                y[3] = (__bf16)((yv[dm][3] - mean) * rstd * g.w + bb.w);
                *(bfv4*)&xs[arow][q * 128 + (j ^ ((q & 7) << 3))] = y;
            }
            __syncthreads();
        } else {
            #pragma unroll
            for (int dm = 0; dm < 4; dm++) {
                int j = h * 64 + dm * 16 + lg * 4;
                float4 g  = *(const float4*)(lgp + j);
                float4 bb = *(const float4*)(lbp + j);
                float4 w  = *(const float4*)(Wl + q * HD_ + j);
                head_partial = fmaf((yv[dm][0] - mean) * rstd * g.x + bb.x, w.x, head_partial);
                head_partial = fmaf((yv[dm][1] - mean) * rstd * g.y + bb.y, w.y, head_partial);
                head_partial = fmaf((yv[dm][2] - mean) * rstd * g.z + bb.z, w.z, head_partial);
                head_partial = fmaf((yv[dm][3] - mean) * rstd * g.w + bb.w, w.w, head_partial);
            }
        }
    }

    // ---- per-row reduction of head partials (red overlays p_lds)
    float* red = (float*)p_lds;
    red[tid] = head_partial;
    __syncthreads();
    if ((wid & 3) == 0) {
        int br = wid >> 2;
        int base = br * 256;
        float s = red[base + lane] + red[base + 64 + lane]
                + red[base + 128 + lane] + red[base + 192 + lane];
        int64_t b0 = (int64_t)blockIdx.x * 2 + br;
        s += h3[b0 * 128 + lane]      * Wl[4096 + lane];
        s += h3[b0 * 128 + 64 + lane] * Wl[4096 + 64 + lane];
        #pragma unroll
        for (int off = 32; off; off >>= 1) s += __shfl_down(s, off);
        if (lane == 0) out[b0] = 1.f / (1.f + __expf(-(s + bl[0])));
    }
}

// ---------------------------------------------------------------------------
extern "C" void kernel_launch(void* const* d_in, const int* in_sizes, int n_in,
                              void* d_out, int out_size, void* d_ws, size_t ws_size,
                              hipStream_t stream)
{
    const int*   tokens       = (const int*)  d_in[0];
    const int*   field_ids    = (const int*)  d_in[1];
    const float* word_emb     = (const float*)d_in[2];
    const float* W_tok        = (const float*)d_in[3];
    const float* field_tables = (const float*)d_in[4];
    const float* Wq           = (const float*)d_in[5];
    const float* Wk           = (const float*)d_in[6];
    const float* Wv           = (const float*)d_in[7];
    const float* Wres         = (const float*)d_in[8];
    const float* ln_g         = (const float*)d_in[9];
    const float* ln_b         = (const float*)d_in[10];
    const float* dnn_W1       = (const float*)d_in[11];
    const float* bn1_g        = (const float*)d_in[12];
    const float* bn1_b        = (const float*)d_in[13];
    const float* bn1_m        = (const float*)d_in[14];
    const float* bn1_v        = (const float*)d_in[15];
    const float* dnn_W2       = (const float*)d_in[16];
    const float* bn2_g        = (const float*)d_in[17];
    const float* bn2_b        = (const float*)d_in[18];
    const float* bn2_m        = (const float*)d_in[19];
    const float* bn2_v        = (const float*)d_in[20];
    const float* dnn_W3       = (const float*)d_in[21];
    const float* dnn_b3       = (const float*)d_in[22];
    const float* W_last       = (const float*)d_in[23];
    const float* b_last       = (const float*)d_in[24];
    float* out = (float*)d_out;

    const int64_t embN = (int64_t)B_ * F_ * E_;          // 16,777,216
    __bf16* embbf = (__bf16*)d_ws;                        // 32 MB
    float*  h3    = (float*)(embbf + embN);               // 2 MB
    __bf16* pkw   = (__bf16*)(h3 + (int64_t)B_ * 128);    // 384 KB
    __bf16* W1t   = pkw + 12 * 16384;                     // 8 MB
    __bf16* W2t   = W1t + (int64_t)1024 * 4096;           // 1 MB
    __bf16* h1bf  = W2t + (int64_t)512 * 1024;            // 8 MB
    float*  h2f   = (float*)(h1bf + (int64_t)B_ * 1024);  // 8 MB

    // weight packing
    pack_weights_kernel<<<dim3(12, 8), 256, 0, stream>>>(Wq, Wk, Wv, Wres, pkw);
    transpose_pack_kernel<<<dim3(64, 16), 256, 0, stream>>>(dnn_W1, W1t, 4096, 1024);
    transpose_pack_kernel<<<dim3(16, 8), 256, 0, stream>>>(dnn_W2, W2t, 1024, 512);

    // embeddings (bf16)
    tok_embed_kernel<<<B_, 128, 0, stream>>>(tokens, word_emb, W_tok, embbf);
    field_gather_kernel<<<(B_ * 31 * 32) / 256, 256, 0, stream>>>(field_ids, field_tables, embbf);

    // DNN tower
    gemm_bt_bf16_bn<1><<<dim3(32, 16), 256, 0, stream>>>(
        embbf, W1t, h1bf, B_, 1024, 4096, bn1_g, bn1_b, bn1_m, bn1_v);
    gemm_bt_bf16_bn<0><<<dim3(32, 8), 256, 0, stream>>>(
        h1bf, W2t, h2f, B_, 512, 1024, bn2_g, bn2_b, bn2_m, bn2_v);
    gemm_bias_f32<<<dim3(64, 2), 256, 0, stream>>>(
        h2f, dnn_W3, h3, B_, 128, 512, dnn_b3);

    // fused attention stack + head, 2 rows per block
    attn3_head_kernel<<<B_ / 2, 512, 0, stream>>>(
        embbf, pkw, ln_g, ln_b, h3, W_last, b_last, out);
}